// Round 1
// baseline (2331.746 us; speedup 1.0000x reference)
//
#include <hip/hip_runtime.h>
#include <hip/hip_bf16.h>

#define DIN 128
#define DH 128
#define DOUTC 64
#define NS 3
#define NL 3
#define EPSV 1e-5f

// ---------------- degree count ----------------
__global__ void k_count(const int* __restrict__ dst, int* __restrict__ counts, int e) {
    int i = blockIdx.x * blockDim.x + threadIdx.x;
    int stride = gridDim.x * blockDim.x;
    for (; i < e; i += stride) atomicAdd(&counts[dst[i]], 1);
}

__global__ void k_dis(const int* __restrict__ counts, float* __restrict__ dis, int n) {
    int i = blockIdx.x * blockDim.x + threadIdx.x;
    if (i < n) dis[i] = rsqrtf((float)counts[i] + 1.0f);
}

// ---------------- exclusive scan (3-phase) ----------------
__global__ void k_scanA(const int* __restrict__ counts, int* __restrict__ row_start,
                        int* __restrict__ bsums, int n) {
    __shared__ int s[512];
    int t = threadIdx.x;
    int i = blockIdx.x * 512 + t;
    int v = (i < n) ? counts[i] : 0;
    s[t] = v;
    __syncthreads();
    for (int off = 1; off < 512; off <<= 1) {
        int x = s[t];
        if (t >= off) x += s[t - off];
        __syncthreads();
        s[t] = x;
        __syncthreads();
    }
    if (i < n) row_start[i] = s[t] - v;           // exclusive within block
    if (t == 511) bsums[blockIdx.x] = s[511];     // block total
}

__global__ void k_scanB(int* __restrict__ bsums, int nb) {
    __shared__ int s[256];
    int t = threadIdx.x;
    int v = (t < nb) ? bsums[t] : 0;
    s[t] = v;
    __syncthreads();
    for (int off = 1; off < 256; off <<= 1) {
        int x = s[t];
        if (t >= off) x += s[t - off];
        __syncthreads();
        s[t] = x;
        __syncthreads();
    }
    if (t < nb) bsums[t] = s[t] - v;              // exclusive block offsets
}

__global__ void k_scanC(int* __restrict__ row_start, const int* __restrict__ bsums, int n) {
    int i = blockIdx.x * blockDim.x + threadIdx.x;
    if (i < n) row_start[i] += bsums[i >> 9];
}

// ---------------- CSR fill ----------------
__global__ void k_fill(const int* __restrict__ src, const int* __restrict__ dst,
                       const int* __restrict__ row_start, int* __restrict__ cursor,
                       int* __restrict__ col, int e) {
    int i = blockIdx.x * blockDim.x + threadIdx.x;
    int stride = gridDim.x * blockDim.x;
    for (; i < e; i += stride) {
        int d = dst[i];
        int p = atomicAdd(&cursor[d], 1);
        col[row_start[d] + p] = src[i];
    }
}

// ---------------- tiny prep: M_s = W2_s @ Wf_s ; b_comb ----------------
__global__ void k_prep(const float* __restrict__ W2, const float* __restrict__ Wf,
                       const float* __restrict__ b2, const float* __restrict__ bf,
                       float* __restrict__ M, float* __restrict__ bcomb) {
    int idx = blockIdx.x * blockDim.x + threadIdx.x;
    if (idx < NS * DH * DOUTC) {
        int s = idx / (DH * DOUTC);
        int rem = idx % (DH * DOUTC);
        int i = rem / DOUTC, j = rem % DOUTC;
        float acc = 0.f;
        for (int c = 0; c < DOUTC; ++c)
            acc += W2[(s * DH + i) * DOUTC + c] * Wf[(s * DOUTC + c) * DOUTC + j];
        M[idx] = acc;
    }
    if (idx < DOUTC) {
        float acc = bf[idx];
        for (int s = 0; s < NS; ++s)
            for (int c = 0; c < DOUTC; ++c)
                acc += b2[s * DOUTC + c] * Wf[(s * DOUTC + c) * DOUTC + idx];
        bcomb[idx] = acc;
    }
}

// ---------------- CSR aggregation: out = D^{-1/2}(A+I)D^{-1/2} in (+bias) ----------------
template <int C, bool BIAS>
__global__ __launch_bounds__(256) void k_aggregate(
        const float* __restrict__ in, float* __restrict__ out,
        const float* __restrict__ dis, const int* __restrict__ row_start,
        const int* __restrict__ counts, const int* __restrict__ col,
        const float* __restrict__ bias, int n) {
    int wid = (blockIdx.x * blockDim.x + threadIdx.x) >> 6;
    int lane = threadIdx.x & 63;
    int nw = (gridDim.x * blockDim.x) >> 6;
    for (int v = wid; v < n; v += nw) {
        float dv = dis[v];
        int st = row_start[v], cnt = counts[v];
        float a0 = 0.f, a1 = 0.f;
        int i = 0;
        for (; i + 4 <= cnt; i += 4) {
            int s0 = col[st + i], s1 = col[st + i + 1], s2 = col[st + i + 2], s3 = col[st + i + 3];
            float w0 = dis[s0], w1 = dis[s1], w2 = dis[s2], w3 = dis[s3];
            a0 += w0 * in[(size_t)s0 * C + lane];
            a0 += w1 * in[(size_t)s1 * C + lane];
            a0 += w2 * in[(size_t)s2 * C + lane];
            a0 += w3 * in[(size_t)s3 * C + lane];
            if (C == 128) {
                a1 += w0 * in[(size_t)s0 * C + 64 + lane];
                a1 += w1 * in[(size_t)s1 * C + 64 + lane];
                a1 += w2 * in[(size_t)s2 * C + 64 + lane];
                a1 += w3 * in[(size_t)s3 * C + 64 + lane];
            }
        }
        for (; i < cnt; ++i) {
            int s0 = col[st + i];
            float w0 = dis[s0];
            a0 += w0 * in[(size_t)s0 * C + lane];
            if (C == 128) a1 += w0 * in[(size_t)s0 * C + 64 + lane];
        }
        float self0 = in[(size_t)v * C + lane];
        float o0 = dv * (a0 + dv * self0);
        if (BIAS) o0 += bias[lane];
        out[(size_t)v * C + lane] = o0;
        if (C == 128) {
            float self1 = in[(size_t)v * C + 64 + lane];
            float o1 = dv * (a1 + dv * self1);
            if (BIAS) o1 += bias[64 + lane];
            out[(size_t)v * C + 64 + lane] = o1;
        }
    }
}

// ---------------- fused GEMM [n,128]@[128,128] + bias + relu + LN ----------------
__global__ __launch_bounds__(256) void k_gemm128_relu_ln(
        const float* __restrict__ in, const float* __restrict__ W,
        const float* __restrict__ bias, const float* __restrict__ gamma,
        const float* __restrict__ beta, float* __restrict__ out, int n, int iters) {
    __shared__ float sW[128 * 128];
    __shared__ float sZ[4][512];
    for (int i = threadIdx.x * 4; i < 128 * 128; i += 256 * 4)
        *(float4*)&sW[i] = *(const float4*)&W[i];
    __syncthreads();
    int wave = threadIdx.x >> 6, lane = threadIdx.x & 63;
    float bi0 = bias[lane], bi1 = bias[64 + lane];
    float g0 = gamma[lane], g1 = gamma[64 + lane];
    float bt0 = beta[lane], bt1 = beta[64 + lane];
    for (int it = 0; it < iters; ++it) {
        int base = (it * gridDim.x + blockIdx.x) * 16 + wave * 4;
        #pragma unroll
        for (int r = 0; r < 4; ++r) {
            int v = base + r;
            if (v < n) {
                sZ[wave][r * 128 + lane] = in[(size_t)v * 128 + lane];
                sZ[wave][r * 128 + 64 + lane] = in[(size_t)v * 128 + 64 + lane];
            }
        }
        asm volatile("s_waitcnt lgkmcnt(0)" ::: "memory");  // wave-local LDS visibility
        float acc[4][2] = {};
        #pragma unroll 4
        for (int k = 0; k < 128; ++k) {
            float w0 = sW[k * 128 + lane];
            float w1 = sW[k * 128 + 64 + lane];
            float z0 = sZ[wave][0 * 128 + k];
            float z1 = sZ[wave][1 * 128 + k];
            float z2 = sZ[wave][2 * 128 + k];
            float z3 = sZ[wave][3 * 128 + k];
            acc[0][0] += z0 * w0; acc[0][1] += z0 * w1;
            acc[1][0] += z1 * w0; acc[1][1] += z1 * w1;
            acc[2][0] += z2 * w0; acc[2][1] += z2 * w1;
            acc[3][0] += z3 * w0; acc[3][1] += z3 * w1;
        }
        #pragma unroll
        for (int r = 0; r < 4; ++r) {
            float y0 = fmaxf(acc[r][0] + bi0, 0.f);
            float y1 = fmaxf(acc[r][1] + bi1, 0.f);
            float s = y0 + y1, q = y0 * y0 + y1 * y1;
            #pragma unroll
            for (int off = 32; off; off >>= 1) {
                s += __shfl_xor(s, off);
                q += __shfl_xor(q, off);
            }
            float mu = s * (1.f / 128.f);
            float var = q * (1.f / 128.f) - mu * mu;
            float rstd = rsqrtf(var + EPSV);
            int v = base + r;
            if (v < n) {
                out[(size_t)v * 128 + lane] = (y0 - mu) * rstd * g0 + bt0;
                out[(size_t)v * 128 + 64 + lane] = (y1 - mu) * rstd * g1 + bt1;
            }
        }
        asm volatile("s_waitcnt lgkmcnt(0)" ::: "memory");
    }
}

// ---------------- GEMM [n,128]@[128,64], optional accumulate ----------------
template <bool ACC>
__global__ __launch_bounds__(256) void k_gemm64(
        const float* __restrict__ in, const float* __restrict__ M,
        float* __restrict__ out, int n, int iters) {
    __shared__ float sW[128 * 64];
    __shared__ float sZ[4][512];
    for (int i = threadIdx.x * 4; i < 128 * 64; i += 256 * 4)
        *(float4*)&sW[i] = *(const float4*)&M[i];
    __syncthreads();
    int wave = threadIdx.x >> 6, lane = threadIdx.x & 63;
    for (int it = 0; it < iters; ++it) {
        int base = (it * gridDim.x + blockIdx.x) * 16 + wave * 4;
        #pragma unroll
        for (int r = 0; r < 4; ++r) {
            int v = base + r;
            if (v < n) {
                sZ[wave][r * 128 + lane] = in[(size_t)v * 128 + lane];
                sZ[wave][r * 128 + 64 + lane] = in[(size_t)v * 128 + 64 + lane];
            }
        }
        asm volatile("s_waitcnt lgkmcnt(0)" ::: "memory");
        float acc[4] = {};
        #pragma unroll 4
        for (int k = 0; k < 128; ++k) {
            float w = sW[k * 64 + lane];
            acc[0] += sZ[wave][0 * 128 + k] * w;
            acc[1] += sZ[wave][1 * 128 + k] * w;
            acc[2] += sZ[wave][2 * 128 + k] * w;
            acc[3] += sZ[wave][3 * 128 + k] * w;
        }
        #pragma unroll
        for (int r = 0; r < 4; ++r) {
            int v = base + r;
            if (v < n) {
                if (ACC) out[(size_t)v * 64 + lane] += acc[r];
                else out[(size_t)v * 64 + lane] = acc[r];
            }
        }
        asm volatile("s_waitcnt lgkmcnt(0)" ::: "memory");
    }
}

extern "C" void kernel_launch(void* const* d_in, const int* in_sizes, int n_in,
                              void* d_out, int out_size, void* d_ws, size_t ws_size,
                              hipStream_t stream) {
    const float* x    = (const float*)d_in[0];
    const int*   ei   = (const int*)d_in[1];
    const float* W0   = (const float*)d_in[2];
    const float* b0   = (const float*)d_in[3];
    const float* W1   = (const float*)d_in[4];
    const float* b1   = (const float*)d_in[5];
    const float* W2   = (const float*)d_in[6];
    const float* b2   = (const float*)d_in[7];
    const float* gamma= (const float*)d_in[8];
    const float* beta = (const float*)d_in[9];
    const float* Wf   = (const float*)d_in[10];
    const float* bf   = (const float*)d_in[11];
    float* out = (float*)d_out;

    const int n = in_sizes[0] / DIN;
    const int e = in_sizes[1] / 2;
    const int* src = ei;
    const int* dst = ei + e;

    char* ws = (char*)d_ws;
    auto alloc = [&](size_t bytes) {
        char* p = ws;
        ws += (bytes + 255) & ~(size_t)255;
        return p;
    };
    int*   counts   = (int*)alloc((size_t)n * 4);
    int*   cursor   = (int*)alloc((size_t)n * 4);
    int*   rowstart = (int*)alloc((size_t)n * 4);
    int*   bsums    = (int*)alloc(4096);
    float* dis      = (float*)alloc((size_t)n * 4);
    int*   col      = (int*)alloc((size_t)e * 4);
    float* M        = (float*)alloc(NS * DH * DOUTC * 4);
    float* bcomb    = (float*)alloc(DOUTC * 4);
    float* z0       = (float*)alloc((size_t)n * DH * 4);
    float* bufA     = (float*)alloc((size_t)n * DH * 4);
    float* bufB     = (float*)alloc((size_t)n * DH * 4);
    float* q        = (float*)alloc((size_t)n * DOUTC * 4);

    hipMemsetAsync(counts, 0, (size_t)n * 4, stream);
    hipMemsetAsync(cursor, 0, (size_t)n * 4, stream);

    k_count<<<2048, 256, 0, stream>>>(dst, counts, e);
    k_dis<<<(n + 255) / 256, 256, 0, stream>>>(counts, dis, n);

    int nb = (n + 511) / 512;  // 196 for n=100000 (fits k_scanB's 256)
    k_scanA<<<nb, 512, 0, stream>>>(counts, rowstart, bsums, n);
    k_scanB<<<1, 256, 0, stream>>>(bsums, nb);
    k_scanC<<<(n + 255) / 256, 256, 0, stream>>>(rowstart, bsums, n);
    k_fill<<<2048, 256, 0, stream>>>(src, dst, rowstart, cursor, col, e);
    k_prep<<<96, 256, 0, stream>>>(W2, Wf, b2, bf, M, bcomb);

    // z0 = P(x)  (shared across scales)
    k_aggregate<128, false><<<1280, 256, 0, stream>>>(x, z0, dis, rowstart, counts, col, nullptr, n);

    const int GB = 1024;
    const int iters = (n + GB * 16 - 1) / (GB * 16);
    for (int s = 0; s < NS; ++s) {
        k_gemm128_relu_ln<<<GB, 256, 0, stream>>>(
            z0, W0 + (size_t)s * DIN * DH, b0 + s * DH,
            gamma + (size_t)(s * NL + 0) * DH, beta + (size_t)(s * NL + 0) * DH, bufA, n, iters);
        k_aggregate<128, false><<<1280, 256, 0, stream>>>(bufA, bufB, dis, rowstart, counts, col, nullptr, n);
        k_gemm128_relu_ln<<<GB, 256, 0, stream>>>(
            bufB, W1 + (size_t)s * DH * DH, b1 + s * DH,
            gamma + (size_t)(s * NL + 1) * DH, beta + (size_t)(s * NL + 1) * DH, bufA, n, iters);
        if (s == 0)
            k_gemm64<false><<<GB, 256, 0, stream>>>(bufA, M + (size_t)s * DH * DOUTC, q, n, iters);
        else
            k_gemm64<true><<<GB, 256, 0, stream>>>(bufA, M + (size_t)s * DH * DOUTC, q, n, iters);
    }
    // out = P(q) + b_comb   (fused layer-2 aggregation + concat + final linear)
    k_aggregate<64, true><<<1280, 256, 0, stream>>>(q, out, dis, rowstart, counts, col, bcomb, n);
}

// Round 2
// 1601.663 us; speedup vs baseline: 1.4558x; 1.4558x over previous
//
#include <hip/hip_runtime.h>

#define DIN 128
#define DH 128
#define DOUTC 64
#define NS 3
#define NL 3
#define EPSV 1e-5f

typedef __attribute__((ext_vector_type(8))) short bf16x8;
typedef __attribute__((ext_vector_type(4))) float f32x4;

static __device__ inline float bf2f(unsigned short h) {
    unsigned int u = ((unsigned int)h) << 16;
    return __builtin_bit_cast(float, u);
}
static __device__ inline unsigned short f2bf(float f) {
    unsigned int u = __builtin_bit_cast(unsigned int, f);
    u += 0x7fffu + ((u >> 16) & 1u);
    return (unsigned short)(u >> 16);
}

// ---------------- degree count ----------------
__global__ void k_count(const int* __restrict__ dst, int* __restrict__ counts, int e) {
    int i = blockIdx.x * blockDim.x + threadIdx.x;
    int stride = gridDim.x * blockDim.x;
    for (; i < e; i += stride) atomicAdd(&counts[dst[i]], 1);
}

__global__ void k_dis(const int* __restrict__ counts, float* __restrict__ dis, int n) {
    int i = blockIdx.x * blockDim.x + threadIdx.x;
    if (i < n) dis[i] = rsqrtf((float)counts[i] + 1.0f);
}

// ---------------- exclusive scan (3-phase) ----------------
__global__ void k_scanA(const int* __restrict__ counts, int* __restrict__ row_start,
                        int* __restrict__ bsums, int n) {
    __shared__ int s[512];
    int t = threadIdx.x;
    int i = blockIdx.x * 512 + t;
    int v = (i < n) ? counts[i] : 0;
    s[t] = v;
    __syncthreads();
    for (int off = 1; off < 512; off <<= 1) {
        int x = s[t];
        if (t >= off) x += s[t - off];
        __syncthreads();
        s[t] = x;
        __syncthreads();
    }
    if (i < n) row_start[i] = s[t] - v;
    if (t == 511) bsums[blockIdx.x] = s[511];
}

__global__ void k_scanB(int* __restrict__ bsums, int nb) {
    __shared__ int s[256];
    int t = threadIdx.x;
    int v = (t < nb) ? bsums[t] : 0;
    s[t] = v;
    __syncthreads();
    for (int off = 1; off < 256; off <<= 1) {
        int x = s[t];
        if (t >= off) x += s[t - off];
        __syncthreads();
        s[t] = x;
        __syncthreads();
    }
    if (t < nb) bsums[t] = s[t] - v;
}

__global__ void k_scanC(int* __restrict__ row_start, const int* __restrict__ bsums, int n) {
    int i = blockIdx.x * blockDim.x + threadIdx.x;
    if (i < n) row_start[i] += bsums[i >> 9];
}

// ---------------- CSR fill ----------------
__global__ void k_fill(const int* __restrict__ src, const int* __restrict__ dst,
                       const int* __restrict__ row_start, int* __restrict__ cursor,
                       int* __restrict__ col, int e) {
    int i = blockIdx.x * blockDim.x + threadIdx.x;
    int stride = gridDim.x * blockDim.x;
    for (; i < e; i += stride) {
        int d = dst[i];
        int p = atomicAdd(&cursor[d], 1);
        col[row_start[d] + p] = src[i];
    }
}

// ---------------- weight prep: transpose + bf16 hi/lo split; Mcat; bcomb ----------------
// Wt0/Wt1: [S][out=128][k=128] so MFMA B-frags read 8 contiguous k's per lane.
// McatT: [out=64][k=384], Mcat[s*128+i][o] = sum_c W2[s][i][c]*Wf[s*64+c][o].
__global__ void k_prep_w(const float* __restrict__ W0, const float* __restrict__ W1,
                         const float* __restrict__ W2, const float* __restrict__ Wf,
                         const float* __restrict__ b2, const float* __restrict__ bf,
                         unsigned short* __restrict__ Wt0hi, unsigned short* __restrict__ Wt0lo,
                         unsigned short* __restrict__ Wt1hi, unsigned short* __restrict__ Wt1lo,
                         unsigned short* __restrict__ Mhi, unsigned short* __restrict__ Mlo,
                         float* __restrict__ bcomb) {
    int idx = blockIdx.x * blockDim.x + threadIdx.x;
    if (idx < NS * DH * DH) {
        int s = idx / (DH * DH);
        int rem = idx % (DH * DH);
        int o = rem / DH, i = rem % DH;
        {
            float v = W0[(size_t)s * DH * DH + (size_t)i * DH + o];
            unsigned short h = f2bf(v);
            Wt0hi[idx] = h;
            Wt0lo[idx] = f2bf(v - bf2f(h));
        }
        {
            float v = W1[(size_t)s * DH * DH + (size_t)i * DH + o];
            unsigned short h = f2bf(v);
            Wt1hi[idx] = h;
            Wt1lo[idx] = f2bf(v - bf2f(h));
        }
    }
    if (idx < DOUTC * NS * DH) {   // 24576: o in [0,64), k in [0,384)
        int o = idx / (NS * DH);
        int k = idx % (NS * DH);
        int s = k / DH, i = k % DH;
        float acc = 0.f;
        for (int c = 0; c < DOUTC; ++c)
            acc += W2[((size_t)s * DH + i) * DOUTC + c] * Wf[((size_t)s * DOUTC + c) * DOUTC + o];
        unsigned short h = f2bf(acc);
        Mhi[idx] = h;
        Mlo[idx] = f2bf(acc - bf2f(h));
    }
    if (idx < DOUTC) {
        float acc = bf[idx];
        for (int s = 0; s < NS; ++s)
            for (int c = 0; c < DOUTC; ++c)
                acc += b2[s * DOUTC + c] * Wf[((size_t)s * DOUTC + c) * DOUTC + idx];
        bcomb[idx] = acc;
    }
}

// ---------------- x -> bf16 ----------------
__global__ void k_cvt(const float2* __restrict__ x, unsigned int* __restrict__ xb, int m) {
    int i = blockIdx.x * blockDim.x + threadIdx.x;
    int stride = gridDim.x * blockDim.x;
    for (; i < m; i += stride) {
        float2 v = x[i];
        xb[i] = ((unsigned int)f2bf(v.y) << 16) | f2bf(v.x);
    }
}

// ---------------- CSR aggregation, 128ch bf16 -> 128ch bf16 ----------------
// in/out viewed as u32 (2 bf16 per lane), one wave per node.
__global__ __launch_bounds__(256) void k_agg128(
        const unsigned int* __restrict__ in, unsigned int* __restrict__ out,
        const float* __restrict__ dis, const int* __restrict__ rowstart,
        const int* __restrict__ counts, const int* __restrict__ col, int n) {
    int wid = (blockIdx.x * blockDim.x + threadIdx.x) >> 6;
    int lane = threadIdx.x & 63;
    int nw = (gridDim.x * blockDim.x) >> 6;
    for (int v = wid; v < n; v += nw) {
        float dv = dis[v];
        int st = rowstart[v], cnt = counts[v];
        float a0 = 0.f, a1 = 0.f;
        int i = 0;
        for (; i + 4 <= cnt; i += 4) {
            int s0 = col[st + i], s1 = col[st + i + 1], s2 = col[st + i + 2], s3 = col[st + i + 3];
            float w0 = dis[s0], w1 = dis[s1], w2 = dis[s2], w3 = dis[s3];
            unsigned int u0 = in[(size_t)s0 * 64 + lane];
            unsigned int u1 = in[(size_t)s1 * 64 + lane];
            unsigned int u2 = in[(size_t)s2 * 64 + lane];
            unsigned int u3 = in[(size_t)s3 * 64 + lane];
            a0 += w0 * __builtin_bit_cast(float, u0 << 16);
            a1 += w0 * __builtin_bit_cast(float, u0 & 0xffff0000u);
            a0 += w1 * __builtin_bit_cast(float, u1 << 16);
            a1 += w1 * __builtin_bit_cast(float, u1 & 0xffff0000u);
            a0 += w2 * __builtin_bit_cast(float, u2 << 16);
            a1 += w2 * __builtin_bit_cast(float, u2 & 0xffff0000u);
            a0 += w3 * __builtin_bit_cast(float, u3 << 16);
            a1 += w3 * __builtin_bit_cast(float, u3 & 0xffff0000u);
        }
        for (; i < cnt; ++i) {
            int s0 = col[st + i];
            float w0 = dis[s0];
            unsigned int u0 = in[(size_t)s0 * 64 + lane];
            a0 += w0 * __builtin_bit_cast(float, u0 << 16);
            a1 += w0 * __builtin_bit_cast(float, u0 & 0xffff0000u);
        }
        unsigned int us = in[(size_t)v * 64 + lane];
        float o0 = dv * (a0 + dv * __builtin_bit_cast(float, us << 16));
        float o1 = dv * (a1 + dv * __builtin_bit_cast(float, us & 0xffff0000u));
        out[(size_t)v * 64 + lane] = ((unsigned int)f2bf(o1) << 16) | f2bf(o0);
    }
}

// ---------------- final aggregation, 64ch bf16 -> 64ch fp32 + bcomb ----------------
// 2 nodes per wave (32 lanes each, 2 ch per lane).
__global__ __launch_bounds__(256) void k_agg64(
        const unsigned int* __restrict__ in, float* __restrict__ out,
        const float* __restrict__ bcomb, const float* __restrict__ dis,
        const int* __restrict__ rowstart, const int* __restrict__ counts,
        const int* __restrict__ col, int n) {
    int wid = (blockIdx.x * blockDim.x + threadIdx.x) >> 6;
    int lane = threadIdx.x & 63;
    int half = lane >> 5, c = lane & 31;
    int nw = (gridDim.x * blockDim.x) >> 6;
    float bc0 = bcomb[c * 2], bc1 = bcomb[c * 2 + 1];
    for (int w = wid; w * 2 < n; w += nw) {
        int v = w * 2 + half;
        if (v >= n) continue;
        float dv = dis[v];
        int st = rowstart[v], cnt = counts[v];
        float a0 = 0.f, a1 = 0.f;
        int i = 0;
        for (; i + 4 <= cnt; i += 4) {
            int s0 = col[st + i], s1 = col[st + i + 1], s2 = col[st + i + 2], s3 = col[st + i + 3];
            float w0 = dis[s0], w1 = dis[s1], w2 = dis[s2], w3 = dis[s3];
            unsigned int u0 = in[(size_t)s0 * 32 + c];
            unsigned int u1 = in[(size_t)s1 * 32 + c];
            unsigned int u2 = in[(size_t)s2 * 32 + c];
            unsigned int u3 = in[(size_t)s3 * 32 + c];
            a0 += w0 * __builtin_bit_cast(float, u0 << 16);
            a1 += w0 * __builtin_bit_cast(float, u0 & 0xffff0000u);
            a0 += w1 * __builtin_bit_cast(float, u1 << 16);
            a1 += w1 * __builtin_bit_cast(float, u1 & 0xffff0000u);
            a0 += w2 * __builtin_bit_cast(float, u2 << 16);
            a1 += w2 * __builtin_bit_cast(float, u2 & 0xffff0000u);
            a0 += w3 * __builtin_bit_cast(float, u3 << 16);
            a1 += w3 * __builtin_bit_cast(float, u3 & 0xffff0000u);
        }
        for (; i < cnt; ++i) {
            int s0 = col[st + i];
            float w0 = dis[s0];
            unsigned int u0 = in[(size_t)s0 * 32 + c];
            a0 += w0 * __builtin_bit_cast(float, u0 << 16);
            a1 += w0 * __builtin_bit_cast(float, u0 & 0xffff0000u);
        }
        unsigned int us = in[(size_t)v * 32 + c];
        float o0 = dv * (a0 + dv * __builtin_bit_cast(float, us << 16)) + bc0;
        float o1 = dv * (a1 + dv * __builtin_bit_cast(float, us & 0xffff0000u)) + bc1;
        float2 o = make_float2(o0, o1);
        *(float2*)&out[(size_t)v * 64 + c * 2] = o;
    }
}

// ---------------- MFMA GEMM: [n, K] bf16 @ Wt(hi+lo) [NT*16, K] -> out bf16 ----------------
// K = KS*32. Per wave: 16 nodes. A-frag: lane holds row (l&15), k = ks*32+(l>>4)*8+j.
// B-frag: lane holds col (l&15), same k mapping (consistent bijection => correct product).
// C/D: col = lane&15 (+16t), row = (lane>>4)*4 + reg   [m89-verified layout]
template <int KS, int NT, bool LN>
__global__ __launch_bounds__(256) void k_gemm_mfma(
        const unsigned short* __restrict__ A, const unsigned short* __restrict__ Whi,
        const unsigned short* __restrict__ Wlo, const float* __restrict__ bias,
        const float* __restrict__ gamma, const float* __restrict__ beta,
        unsigned short* __restrict__ out, int ldc, int colofs, int n) {
    constexpr int K = KS * 32;
    int wave = threadIdx.x >> 6, lane = threadIdx.x & 63;
    int g = blockIdx.x * 4 + wave;
    if (g * 16 >= n) return;
    int r16 = lane & 15, g4 = lane >> 4;
    int row = g * 16 + r16;

    f32x4 acc[NT];
    #pragma unroll
    for (int t = 0; t < NT; ++t) acc[t] = (f32x4){0.f, 0.f, 0.f, 0.f};

    #pragma unroll
    for (int ks = 0; ks < KS; ++ks) {
        bf16x8 a = *(const bf16x8*)&A[(size_t)row * K + ks * 32 + g4 * 8];
        #pragma unroll
        for (int t = 0; t < NT; ++t) {
            size_t wofs = (size_t)(t * 16 + r16) * K + ks * 32 + g4 * 8;
            bf16x8 bh = *(const bf16x8*)&Whi[wofs];
            bf16x8 bl = *(const bf16x8*)&Wlo[wofs];
            acc[t] = __builtin_amdgcn_mfma_f32_16x16x32_bf16(a, bh, acc[t], 0, 0, 0);
            acc[t] = __builtin_amdgcn_mfma_f32_16x16x32_bf16(a, bl, acc[t], 0, 0, 0);
        }
    }

    if (LN) {
        float bia[NT], gam[NT], bet[NT];
        #pragma unroll
        for (int t = 0; t < NT; ++t) {
            bia[t] = bias[t * 16 + r16];
            gam[t] = gamma[t * 16 + r16];
            bet[t] = beta[t * 16 + r16];
        }
        #pragma unroll
        for (int r = 0; r < 4; ++r) {
            float y[NT];
            float s = 0.f, q = 0.f;
            #pragma unroll
            for (int t = 0; t < NT; ++t) {
                y[t] = fmaxf(acc[t][r] + bia[t], 0.f);
                s += y[t];
                q += y[t] * y[t];
            }
            #pragma unroll
            for (int off = 8; off; off >>= 1) {
                s += __shfl_xor(s, off);
                q += __shfl_xor(q, off);
            }
            float mu = s * (1.f / (NT * 16));
            float var = q * (1.f / (NT * 16)) - mu * mu;
            float rstd = rsqrtf(var + EPSV);
            int node = g * 16 + g4 * 4 + r;
            #pragma unroll
            for (int t = 0; t < NT; ++t) {
                float o = (y[t] - mu) * rstd * gam[t] + bet[t];
                out[(size_t)node * ldc + colofs + t * 16 + r16] = f2bf(o);
            }
        }
    } else {
        #pragma unroll
        for (int r = 0; r < 4; ++r) {
            int node = g * 16 + g4 * 4 + r;
            #pragma unroll
            for (int t = 0; t < NT; ++t)
                out[(size_t)node * ldc + colofs + t * 16 + r16] = f2bf(acc[t][r]);
        }
    }
}

extern "C" void kernel_launch(void* const* d_in, const int* in_sizes, int n_in,
                              void* d_out, int out_size, void* d_ws, size_t ws_size,
                              hipStream_t stream) {
    const float* x    = (const float*)d_in[0];
    const int*   ei   = (const int*)d_in[1];
    const float* W0   = (const float*)d_in[2];
    const float* b0   = (const float*)d_in[3];
    const float* W1   = (const float*)d_in[4];
    const float* b1   = (const float*)d_in[5];
    const float* W2   = (const float*)d_in[6];
    const float* b2   = (const float*)d_in[7];
    const float* gamma= (const float*)d_in[8];
    const float* beta = (const float*)d_in[9];
    const float* Wf   = (const float*)d_in[10];
    const float* bf   = (const float*)d_in[11];
    float* out = (float*)d_out;

    const int n = in_sizes[0] / DIN;
    const int e = in_sizes[1] / 2;
    const int* src = ei;
    const int* dst = ei + e;

    char* ws = (char*)d_ws;
    auto alloc = [&](size_t bytes) {
        char* p = ws;
        ws += (bytes + 255) & ~(size_t)255;
        return p;
    };
    int*   counts   = (int*)alloc((size_t)n * 4);
    int*   cursor   = (int*)alloc((size_t)n * 4);
    int*   rowstart = (int*)alloc((size_t)n * 4);
    int*   bsums    = (int*)alloc(4096);
    float* dis      = (float*)alloc((size_t)n * 4);
    int*   col      = (int*)alloc((size_t)e * 4);
    unsigned short* Wt0hi = (unsigned short*)alloc((size_t)NS * DH * DH * 2);
    unsigned short* Wt0lo = (unsigned short*)alloc((size_t)NS * DH * DH * 2);
    unsigned short* Wt1hi = (unsigned short*)alloc((size_t)NS * DH * DH * 2);
    unsigned short* Wt1lo = (unsigned short*)alloc((size_t)NS * DH * DH * 2);
    unsigned short* Mhi   = (unsigned short*)alloc((size_t)DOUTC * NS * DH * 2);
    unsigned short* Mlo   = (unsigned short*)alloc((size_t)DOUTC * NS * DH * 2);
    float* bcomb    = (float*)alloc(DOUTC * 4);
    unsigned short* xb    = (unsigned short*)alloc((size_t)n * DIN * 2);
    unsigned short* z0    = (unsigned short*)alloc((size_t)n * DH * 2);
    unsigned short* h1    = (unsigned short*)alloc((size_t)n * DH * 2);
    unsigned short* g1    = (unsigned short*)alloc((size_t)n * DH * 2);
    unsigned short* h2cat = (unsigned short*)alloc((size_t)n * NS * DH * 2);
    unsigned short* q     = (unsigned short*)alloc((size_t)n * DOUTC * 2);

    hipMemsetAsync(counts, 0, (size_t)n * 4, stream);
    hipMemsetAsync(cursor, 0, (size_t)n * 4, stream);

    k_count<<<2048, 256, 0, stream>>>(dst, counts, e);
    k_dis<<<(n + 255) / 256, 256, 0, stream>>>(counts, dis, n);

    int nb = (n + 511) / 512;
    k_scanA<<<nb, 512, 0, stream>>>(counts, rowstart, bsums, n);
    k_scanB<<<1, 256, 0, stream>>>(bsums, nb);
    k_scanC<<<(n + 255) / 256, 256, 0, stream>>>(rowstart, bsums, n);
    k_fill<<<2048, 256, 0, stream>>>(src, dst, rowstart, cursor, col, e);

    k_prep_w<<<(NS * DH * DH + 255) / 256, 256, 0, stream>>>(
        W0, W1, W2, Wf, b2, bf, Wt0hi, Wt0lo, Wt1hi, Wt1lo, Mhi, Mlo, bcomb);
    k_cvt<<<2048, 256, 0, stream>>>((const float2*)x, (unsigned int*)xb, n * DIN / 2);

    // z0 = P(xb)  (shared across scales)
    k_agg128<<<1280, 256, 0, stream>>>((const unsigned int*)xb, (unsigned int*)z0,
                                       dis, rowstart, counts, col, n);

    const int GG = (n / 16 + 3) / 4;   // blocks of 4 waves x 16 nodes
    for (int s = 0; s < NS; ++s) {
        // h1 = LN(relu(z0 @ W0_s + b0_s))
        k_gemm_mfma<4, 8, true><<<GG, 256, 0, stream>>>(
            xb /*dummy avoid*/ == nullptr ? nullptr : z0,
            Wt0hi + (size_t)s * DH * DH, Wt0lo + (size_t)s * DH * DH,
            b0 + s * DH, gamma + (size_t)(s * NL + 0) * DH, beta + (size_t)(s * NL + 0) * DH,
            h1, DH, 0, n);
        // g1 = P(h1)
        k_agg128<<<1280, 256, 0, stream>>>((const unsigned int*)h1, (unsigned int*)g1,
                                           dis, rowstart, counts, col, n);
        // h2cat[:, s*128:(s+1)*128] = LN(relu(g1 @ W1_s + b1_s))
        k_gemm_mfma<4, 8, true><<<GG, 256, 0, stream>>>(
            g1, Wt1hi + (size_t)s * DH * DH, Wt1lo + (size_t)s * DH * DH,
            b1 + s * DH, gamma + (size_t)(s * NL + 1) * DH, beta + (size_t)(s * NL + 1) * DH,
            h2cat, NS * DH, s * DH, n);
    }
    // q = h2cat @ Mcat   (layer-2 weight folded with final projection)
    k_gemm_mfma<12, 4, false><<<GG, 256, 0, stream>>>(
        h2cat, Mhi, Mlo, nullptr, nullptr, nullptr, q, DOUTC, 0, n);
    // out = P(q) + bcomb
    k_agg64<<<1280, 256, 0, stream>>>((const unsigned int*)q, out, bcomb,
                                      dis, rowstart, counts, col, n);
}

// Round 4
// 1505.893 us; speedup vs baseline: 1.5484x; 1.0636x over previous
//
#include <hip/hip_runtime.h>

#define DIN 128
#define DH 128
#define DOUTC 64
#define NS 3
#define NL 3
#define EPSV 1e-5f

typedef __attribute__((ext_vector_type(8))) short bf16x8;
typedef __attribute__((ext_vector_type(4))) float f32x4;

static __device__ inline float bf2f(unsigned short h) {
    unsigned int u = ((unsigned int)h) << 16;
    return __builtin_bit_cast(float, u);
}
static __device__ inline unsigned short f2bf(float f) {
    unsigned int u = __builtin_bit_cast(unsigned int, f);
    u += 0x7fffu + ((u >> 16) & 1u);
    return (unsigned short)(u >> 16);
}
static __device__ inline float lo16(unsigned int u) {
    return __builtin_bit_cast(float, u << 16);
}
static __device__ inline float hi16(unsigned int u) {
    return __builtin_bit_cast(float, u & 0xffff0000u);
}

// ---------------- degree count, XCD-range-localized ----------------
__global__ __launch_bounds__(256) void k_count_r(const int* __restrict__ dst,
                                                 int* __restrict__ counts, int e, int n) {
    int rg = blockIdx.x & 7;
    int lo = rg * (n >> 3);
    int hi = (rg == 7) ? n : lo + (n >> 3);
    int nb = gridDim.x >> 3, bi = blockIdx.x >> 3;
    for (int i = bi * 256 + threadIdx.x; i < e; i += nb * 256) {
        int d = dst[i];
        if (d >= lo && d < hi) atomicAdd(&counts[d], 1);
    }
}

__global__ void k_dis(const int* __restrict__ counts, float* __restrict__ dis, int n) {
    int i = blockIdx.x * blockDim.x + threadIdx.x;
    if (i < n) dis[i] = rsqrtf((float)counts[i] + 1.0f);
}

// ---------------- exclusive scan (3-phase) ----------------
__global__ void k_scanA(const int* __restrict__ counts, int* __restrict__ row_start,
                        int* __restrict__ bsums, int n) {
    __shared__ int s[512];
    int t = threadIdx.x;
    int i = blockIdx.x * 512 + t;
    int v = (i < n) ? counts[i] : 0;
    s[t] = v;
    __syncthreads();
    for (int off = 1; off < 512; off <<= 1) {
        int x = s[t];
        if (t >= off) x += s[t - off];
        __syncthreads();
        s[t] = x;
        __syncthreads();
    }
    if (i < n) row_start[i] = s[t] - v;
    if (t == 511) bsums[blockIdx.x] = s[511];
}

__global__ void k_scanB(int* __restrict__ bsums, int nb) {
    __shared__ int s[256];
    int t = threadIdx.x;
    int v = (t < nb) ? bsums[t] : 0;
    s[t] = v;
    __syncthreads();
    for (int off = 1; off < 256; off <<= 1) {
        int x = s[t];
        if (t >= off) x += s[t - off];
        __syncthreads();
        s[t] = x;
        __syncthreads();
    }
    if (t < nb) bsums[t] = s[t] - v;
}

__global__ void k_scanC(int* __restrict__ row_start, const int* __restrict__ bsums, int n) {
    int i = blockIdx.x * blockDim.x + threadIdx.x;
    if (i < n) row_start[i] += bsums[i >> 9];
}

// ---------------- CSR fill, XCD-range-localized ----------------
__global__ __launch_bounds__(256) void k_fill_r(const int* __restrict__ src,
                                                const int* __restrict__ dst,
                                                const int* __restrict__ row_start,
                                                int* __restrict__ cursor,
                                                int* __restrict__ col, int e, int n) {
    int rg = blockIdx.x & 7;
    int lo = rg * (n >> 3);
    int hi = (rg == 7) ? n : lo + (n >> 3);
    int nb = gridDim.x >> 3, bi = blockIdx.x >> 3;
    for (int i = bi * 256 + threadIdx.x; i < e; i += nb * 256) {
        int d = dst[i];
        int s = src[i];
        if (d >= lo && d < hi) {
            int p = atomicAdd(&cursor[d], 1);
            col[row_start[d] + p] = s;
        }
    }
}

// ---------------- weight prep: transpose + bf16 hi/lo split; Mcat; bcomb ----------------
__global__ void k_prep_w(const float* __restrict__ W0, const float* __restrict__ W1,
                         const float* __restrict__ W2, const float* __restrict__ Wf,
                         const float* __restrict__ b2, const float* __restrict__ bf,
                         unsigned short* __restrict__ Wt0hi, unsigned short* __restrict__ Wt0lo,
                         unsigned short* __restrict__ Wt1hi, unsigned short* __restrict__ Wt1lo,
                         unsigned short* __restrict__ Mhi, unsigned short* __restrict__ Mlo,
                         float* __restrict__ bcomb) {
    int idx = blockIdx.x * blockDim.x + threadIdx.x;
    if (idx < NS * DH * DH) {
        int s = idx / (DH * DH);
        int rem = idx % (DH * DH);
        int o = rem / DH, i = rem % DH;
        {
            float v = W0[(size_t)s * DH * DH + (size_t)i * DH + o];
            unsigned short h = f2bf(v);
            Wt0hi[idx] = h;
            Wt0lo[idx] = f2bf(v - bf2f(h));
        }
        {
            float v = W1[(size_t)s * DH * DH + (size_t)i * DH + o];
            unsigned short h = f2bf(v);
            Wt1hi[idx] = h;
            Wt1lo[idx] = f2bf(v - bf2f(h));
        }
    }
    if (idx < DOUTC * NS * DH) {   // o in [0,64), k in [0,384)
        int o = idx / (NS * DH);
        int k = idx % (NS * DH);
        int s = k / DH, i = k % DH;
        float acc = 0.f;
        for (int c = 0; c < DOUTC; ++c)
            acc += W2[((size_t)s * DH + i) * DOUTC + c] * Wf[((size_t)s * DOUTC + c) * DOUTC + o];
        unsigned short h = f2bf(acc);
        Mhi[idx] = h;
        Mlo[idx] = f2bf(acc - bf2f(h));
    }
    if (idx < DOUTC) {
        float acc = bf[idx];
        for (int s = 0; s < NS; ++s)
            for (int c = 0; c < DOUTC; ++c)
                acc += b2[s * DOUTC + c] * Wf[((size_t)s * DOUTC + c) * DOUTC + idx];
        bcomb[idx] = acc;
    }
}

// ---------------- x -> bf16 ----------------
__global__ void k_cvt(const float2* __restrict__ x, unsigned int* __restrict__ xb, int m) {
    int i = blockIdx.x * blockDim.x + threadIdx.x;
    int stride = gridDim.x * blockDim.x;
    for (; i < m; i += stride) {
        float2 v = x[i];
        xb[i] = ((unsigned int)f2bf(v.y) << 16) | f2bf(v.x);
    }
}

// ---------------- CSR aggregation, 128ch bf16 -> 128ch bf16 ----------------
__global__ __launch_bounds__(256) void k_agg128(
        const unsigned int* __restrict__ in, unsigned int* __restrict__ out,
        const float* __restrict__ dis, const int* __restrict__ rowstart,
        const int* __restrict__ counts, const int* __restrict__ col, int n) {
    int wid = (blockIdx.x * blockDim.x + threadIdx.x) >> 6;
    int lane = threadIdx.x & 63;
    int nw = (gridDim.x * blockDim.x) >> 6;
    for (int v = wid; v < n; v += nw) {
        float dv = dis[v];
        int st = rowstart[v], cnt = counts[v];
        float a0 = 0.f, a1 = 0.f;
        int i = 0;
        for (; i + 4 <= cnt; i += 4) {
            int s0 = col[st + i], s1 = col[st + i + 1], s2 = col[st + i + 2], s3 = col[st + i + 3];
            float w0 = dis[s0], w1 = dis[s1], w2 = dis[s2], w3 = dis[s3];
            unsigned int u0 = in[(size_t)s0 * 64 + lane];
            unsigned int u1 = in[(size_t)s1 * 64 + lane];
            unsigned int u2 = in[(size_t)s2 * 64 + lane];
            unsigned int u3 = in[(size_t)s3 * 64 + lane];
            a0 += w0 * lo16(u0); a1 += w0 * hi16(u0);
            a0 += w1 * lo16(u1); a1 += w1 * hi16(u1);
            a0 += w2 * lo16(u2); a1 += w2 * hi16(u2);
            a0 += w3 * lo16(u3); a1 += w3 * hi16(u3);
        }
        for (; i < cnt; ++i) {
            int s0 = col[st + i];
            float w0 = dis[s0];
            unsigned int u0 = in[(size_t)s0 * 64 + lane];
            a0 += w0 * lo16(u0); a1 += w0 * hi16(u0);
        }
        unsigned int us = in[(size_t)v * 64 + lane];
        float o0 = dv * (a0 + dv * lo16(us));
        float o1 = dv * (a1 + dv * hi16(us));
        out[(size_t)v * 64 + lane] = ((unsigned int)f2bf(o1) << 16) | f2bf(o0);
    }
}

// ---------------- batched CSR aggregation, 384ch bf16 -> 384ch bf16 ----------------
// row = 192 u32; lane covers u32 indices {lane, lane+64, lane+128}.
__global__ __launch_bounds__(256) void k_agg384(
        const unsigned int* __restrict__ in, unsigned int* __restrict__ out,
        const float* __restrict__ dis, const int* __restrict__ rowstart,
        const int* __restrict__ counts, const int* __restrict__ col, int n) {
    int wid = (blockIdx.x * blockDim.x + threadIdx.x) >> 6;
    int lane = threadIdx.x & 63;
    int nw = (gridDim.x * blockDim.x) >> 6;
    for (int v = wid; v < n; v += nw) {
        float dv = dis[v];
        int st = rowstart[v], cnt = counts[v];
        float a0 = 0.f, a1 = 0.f, a2 = 0.f, a3 = 0.f, a4 = 0.f, a5 = 0.f;
        int i = 0;
        for (; i + 2 <= cnt; i += 2) {
            int s0 = col[st + i], s1 = col[st + i + 1];
            float w0 = dis[s0], w1 = dis[s1];
            const unsigned int* p0 = in + (size_t)s0 * 192;
            const unsigned int* p1 = in + (size_t)s1 * 192;
            unsigned int u00 = p0[lane], u01 = p0[lane + 64], u02 = p0[lane + 128];
            unsigned int u10 = p1[lane], u11 = p1[lane + 64], u12 = p1[lane + 128];
            a0 += w0 * lo16(u00); a1 += w0 * hi16(u00);
            a2 += w0 * lo16(u01); a3 += w0 * hi16(u01);
            a4 += w0 * lo16(u02); a5 += w0 * hi16(u02);
            a0 += w1 * lo16(u10); a1 += w1 * hi16(u10);
            a2 += w1 * lo16(u11); a3 += w1 * hi16(u11);
            a4 += w1 * lo16(u12); a5 += w1 * hi16(u12);
        }
        for (; i < cnt; ++i) {
            int s0 = col[st + i];
            float w0 = dis[s0];
            const unsigned int* p0 = in + (size_t)s0 * 192;
            unsigned int u00 = p0[lane], u01 = p0[lane + 64], u02 = p0[lane + 128];
            a0 += w0 * lo16(u00); a1 += w0 * hi16(u00);
            a2 += w0 * lo16(u01); a3 += w0 * hi16(u01);
            a4 += w0 * lo16(u02); a5 += w0 * hi16(u02);
        }
        const unsigned int* ps = in + (size_t)v * 192;
        unsigned int us0 = ps[lane], us1 = ps[lane + 64], us2 = ps[lane + 128];
        float o0 = dv * (a0 + dv * lo16(us0));
        float o1 = dv * (a1 + dv * hi16(us0));
        float o2 = dv * (a2 + dv * lo16(us1));
        float o3 = dv * (a3 + dv * hi16(us1));
        float o4 = dv * (a4 + dv * lo16(us2));
        float o5 = dv * (a5 + dv * hi16(us2));
        unsigned int* po = out + (size_t)v * 192;
        po[lane]       = ((unsigned int)f2bf(o1) << 16) | f2bf(o0);
        po[lane + 64]  = ((unsigned int)f2bf(o3) << 16) | f2bf(o2);
        po[lane + 128] = ((unsigned int)f2bf(o5) << 16) | f2bf(o4);
    }
}

// ---------------- final aggregation, 64ch bf16 -> 64ch fp32 + bcomb ----------------
__global__ __launch_bounds__(256) void k_agg64(
        const unsigned int* __restrict__ in, float* __restrict__ out,
        const float* __restrict__ bcomb, const float* __restrict__ dis,
        const int* __restrict__ rowstart, const int* __restrict__ counts,
        const int* __restrict__ col, int n) {
    int wid = (blockIdx.x * blockDim.x + threadIdx.x) >> 6;
    int lane = threadIdx.x & 63;
    int half = lane >> 5, c = lane & 31;
    int nw = (gridDim.x * blockDim.x) >> 6;
    float bc0 = bcomb[c * 2], bc1 = bcomb[c * 2 + 1];
    for (int w = wid; w * 2 < n; w += nw) {
        int v = w * 2 + half;
        if (v >= n) continue;
        float dv = dis[v];
        int st = rowstart[v], cnt = counts[v];
        float a0 = 0.f, a1 = 0.f;
        int i = 0;
        for (; i + 4 <= cnt; i += 4) {
            int s0 = col[st + i], s1 = col[st + i + 1], s2 = col[st + i + 2], s3 = col[st + i + 3];
            float w0 = dis[s0], w1 = dis[s1], w2 = dis[s2], w3 = dis[s3];
            unsigned int u0 = in[(size_t)s0 * 32 + c];
            unsigned int u1 = in[(size_t)s1 * 32 + c];
            unsigned int u2 = in[(size_t)s2 * 32 + c];
            unsigned int u3 = in[(size_t)s3 * 32 + c];
            a0 += w0 * lo16(u0); a1 += w0 * hi16(u0);
            a0 += w1 * lo16(u1); a1 += w1 * hi16(u1);
            a0 += w2 * lo16(u2); a1 += w2 * hi16(u2);
            a0 += w3 * lo16(u3); a1 += w3 * hi16(u3);
        }
        for (; i < cnt; ++i) {
            int s0 = col[st + i];
            float w0 = dis[s0];
            unsigned int u0 = in[(size_t)s0 * 32 + c];
            a0 += w0 * lo16(u0); a1 += w0 * hi16(u0);
        }
        unsigned int us = in[(size_t)v * 32 + c];
        float o0 = dv * (a0 + dv * lo16(us)) + bc0;
        float o1 = dv * (a1 + dv * hi16(us)) + bc1;
        float2 o = make_float2(o0, o1);
        *(float2*)&out[(size_t)v * 64 + c * 2] = o;
    }
}

// ---------------- fused layer-0 GEMM: z0 @ W0_s for s=0..2 -> h1cat [n][384] ----------------
// A-frag: lane holds row (l&15), k = ks*32+(l>>4)*8+j. B same bijection.
// C/D: col=lane&15 (+16t), row=(lane>>4)*4+reg  [m89-verified]
__global__ __launch_bounds__(256) void k_gemm0(
        const unsigned short* __restrict__ A, const unsigned short* __restrict__ Whi,
        const unsigned short* __restrict__ Wlo, const float* __restrict__ bias,
        const float* __restrict__ gamma, const float* __restrict__ beta,
        unsigned short* __restrict__ out, int n) {
    int wave = threadIdx.x >> 6, lane = threadIdx.x & 63;
    int g = blockIdx.x * 4 + wave;
    if (g * 16 >= n) return;
    int r16 = lane & 15, g4 = lane >> 4;
    int row = g * 16 + r16;
    if (row >= n) row = n - 1;

    bf16x8 a[4];
    #pragma unroll
    for (int ks = 0; ks < 4; ++ks)
        a[ks] = *(const bf16x8*)&A[(size_t)row * DH + ks * 32 + g4 * 8];

    for (int s = 0; s < NS; ++s) {
        const unsigned short* whi = Whi + (size_t)s * DH * DH;
        const unsigned short* wlo = Wlo + (size_t)s * DH * DH;
        f32x4 acc[8];
        #pragma unroll
        for (int t = 0; t < 8; ++t) acc[t] = (f32x4){0.f, 0.f, 0.f, 0.f};
        #pragma unroll
        for (int ks = 0; ks < 4; ++ks) {
            #pragma unroll
            for (int t = 0; t < 8; ++t) {
                size_t wofs = (size_t)(t * 16 + r16) * DH + ks * 32 + g4 * 8;
                bf16x8 bh = *(const bf16x8*)&whi[wofs];
                bf16x8 bl = *(const bf16x8*)&wlo[wofs];
                acc[t] = __builtin_amdgcn_mfma_f32_16x16x32_bf16(a[ks], bh, acc[t], 0, 0, 0);
                acc[t] = __builtin_amdgcn_mfma_f32_16x16x32_bf16(a[ks], bl, acc[t], 0, 0, 0);
            }
        }
        float bia[8], gam[8], bet[8];
        #pragma unroll
        for (int t = 0; t < 8; ++t) {
            bia[t] = bias[s * DH + t * 16 + r16];
            gam[t] = gamma[(size_t)(s * NL + 0) * DH + t * 16 + r16];
            bet[t] = beta[(size_t)(s * NL + 0) * DH + t * 16 + r16];
        }
        #pragma unroll
        for (int r = 0; r < 4; ++r) {
            float y[8];
            float sm = 0.f, q = 0.f;
            #pragma unroll
            for (int t = 0; t < 8; ++t) {
                y[t] = fmaxf(acc[t][r] + bia[t], 0.f);
                sm += y[t];
                q += y[t] * y[t];
            }
            #pragma unroll
            for (int off = 8; off; off >>= 1) {
                sm += __shfl_xor(sm, off);
                q += __shfl_xor(q, off);
            }
            float mu = sm * (1.f / 128.f);
            float var = q * (1.f / 128.f) - mu * mu;
            float rstd = rsqrtf(var + EPSV);
            int node = g * 16 + g4 * 4 + r;
            if (node < n) {
                #pragma unroll
                for (int t = 0; t < 8; ++t) {
                    float o = (y[t] - mu) * rstd * gam[t] + bet[t];
                    out[(size_t)node * (NS * DH) + s * DH + t * 16 + r16] = f2bf(o);
                }
            }
        }
    }
}

// ---------------- fused layer-1 GEMM + folded final GEMM ----------------
// g1cat [n][384] -> per scale LN(relu(.@W1_s+b1_s)) staged in LDS -> @ Mcat[64][384] -> q [n][64]
__global__ __launch_bounds__(256) void k_gemm1q(
        const unsigned short* __restrict__ G, const unsigned short* __restrict__ Whi,
        const unsigned short* __restrict__ Wlo, const unsigned short* __restrict__ Mhi,
        const unsigned short* __restrict__ Mlo, const float* __restrict__ bias,
        const float* __restrict__ gamma, const float* __restrict__ beta,
        unsigned short* __restrict__ q, int n) {
    __shared__ __align__(16) unsigned short sH[4][16][392];
    int wave = threadIdx.x >> 6, lane = threadIdx.x & 63;
    int g = blockIdx.x * 4 + wave;
    if (g * 16 >= n) return;
    int r16 = lane & 15, g4 = lane >> 4;
    int row = g * 16 + r16;
    if (row >= n) row = n - 1;

    for (int s = 0; s < NS; ++s) {
        bf16x8 a[4];
        #pragma unroll
        for (int ks = 0; ks < 4; ++ks)
            a[ks] = *(const bf16x8*)&G[(size_t)row * (NS * DH) + s * DH + ks * 32 + g4 * 8];
        const unsigned short* whi = Whi + (size_t)s * DH * DH;
        const unsigned short* wlo = Wlo + (size_t)s * DH * DH;
        f32x4 acc[8];
        #pragma unroll
        for (int t = 0; t < 8; ++t) acc[t] = (f32x4){0.f, 0.f, 0.f, 0.f};
        #pragma unroll
        for (int ks = 0; ks < 4; ++ks) {
            #pragma unroll
            for (int t = 0; t < 8; ++t) {
                size_t wofs = (size_t)(t * 16 + r16) * DH + ks * 32 + g4 * 8;
                bf16x8 bh = *(const bf16x8*)&whi[wofs];
                bf16x8 bl = *(const bf16x8*)&wlo[wofs];
                acc[t] = __builtin_amdgcn_mfma_f32_16x16x32_bf16(a[ks], bh, acc[t], 0, 0, 0);
                acc[t] = __builtin_amdgcn_mfma_f32_16x16x32_bf16(a[ks], bl, acc[t], 0, 0, 0);
            }
        }
        float bia[8], gam[8], bet[8];
        #pragma unroll
        for (int t = 0; t < 8; ++t) {
            bia[t] = bias[s * DH + t * 16 + r16];
            gam[t] = gamma[(size_t)(s * NL + 1) * DH + t * 16 + r16];
            bet[t] = beta[(size_t)(s * NL + 1) * DH + t * 16 + r16];
        }
        #pragma unroll
        for (int r = 0; r < 4; ++r) {
            float y[8];
            float sm = 0.f, qq = 0.f;
            #pragma unroll
            for (int t = 0; t < 8; ++t) {
                y[t] = fmaxf(acc[t][r] + bia[t], 0.f);
                sm += y[t];
                qq += y[t] * y[t];
            }
            #pragma unroll
            for (int off = 8; off; off >>= 1) {
                sm += __shfl_xor(sm, off);
                qq += __shfl_xor(qq, off);
            }
            float mu = sm * (1.f / 128.f);
            float var = qq * (1.f / 128.f) - mu * mu;
            float rstd = rsqrtf(var + EPSV);
            #pragma unroll
            for (int t = 0; t < 8; ++t) {
                float o = (y[t] - mu) * rstd * gam[t] + bet[t];
                sH[wave][g4 * 4 + r][s * DH + t * 16 + r16] = f2bf(o);
            }
        }
    }
    __syncthreads();
    // q-GEMM: [16][384] @ Mcat^T[64][384]
    f32x4 qa[4];
    #pragma unroll
    for (int t = 0; t < 4; ++t) qa[t] = (f32x4){0.f, 0.f, 0.f, 0.f};
    #pragma unroll
    for (int ks = 0; ks < 12; ++ks) {
        bf16x8 av = *(const bf16x8*)&sH[wave][r16][ks * 32 + g4 * 8];
        #pragma unroll
        for (int t = 0; t < 4; ++t) {
            size_t wofs = (size_t)(t * 16 + r16) * (NS * DH) + ks * 32 + g4 * 8;
            bf16x8 bh = *(const bf16x8*)&Mhi[wofs];
            bf16x8 bl = *(const bf16x8*)&Mlo[wofs];
            qa[t] = __builtin_amdgcn_mfma_f32_16x16x32_bf16(av, bh, qa[t], 0, 0, 0);
            qa[t] = __builtin_amdgcn_mfma_f32_16x16x32_bf16(av, bl, qa[t], 0, 0, 0);
        }
    }
    #pragma unroll
    for (int r = 0; r < 4; ++r) {
        int node = g * 16 + g4 * 4 + r;
        if (node < n) {
            #pragma unroll
            for (int t = 0; t < 4; ++t)
                q[(size_t)node * DOUTC + t * 16 + r16] = f2bf(qa[t][r]);
        }
    }
}

extern "C" void kernel_launch(void* const* d_in, const int* in_sizes, int n_in,
                              void* d_out, int out_size, void* d_ws, size_t ws_size,
                              hipStream_t stream) {
    const float* x    = (const float*)d_in[0];
    const int*   ei   = (const int*)d_in[1];
    const float* W0   = (const float*)d_in[2];
    const float* b0   = (const float*)d_in[3];
    const float* W1   = (const float*)d_in[4];
    const float* b1   = (const float*)d_in[5];
    const float* W2   = (const float*)d_in[6];
    const float* b2   = (const float*)d_in[7];
    const float* gamma= (const float*)d_in[8];
    const float* beta = (const float*)d_in[9];
    const float* Wf   = (const float*)d_in[10];
    const float* bf   = (const float*)d_in[11];
    float* out = (float*)d_out;

    const int n = in_sizes[0] / DIN;
    const int e = in_sizes[1] / 2;
    const int* src = ei;
    const int* dst = ei + e;

    char* ws = (char*)d_ws;
    auto alloc = [&](size_t bytes) {
        char* p = ws;
        ws += (bytes + 255) & ~(size_t)255;
        return p;
    };
    int*   counts   = (int*)alloc((size_t)n * 4);
    int*   cursor   = (int*)alloc((size_t)n * 4);
    int*   rowstart = (int*)alloc((size_t)n * 4);
    int*   bsums    = (int*)alloc(4096);
    float* dis      = (float*)alloc((size_t)n * 4);
    int*   col      = (int*)alloc((size_t)e * 4);
    unsigned short* Wt0hi = (unsigned short*)alloc((size_t)NS * DH * DH * 2);
    unsigned short* Wt0lo = (unsigned short*)alloc((size_t)NS * DH * DH * 2);
    unsigned short* Wt1hi = (unsigned short*)alloc((size_t)NS * DH * DH * 2);
    unsigned short* Wt1lo = (unsigned short*)alloc((size_t)NS * DH * DH * 2);
    unsigned short* Mhi   = (unsigned short*)alloc((size_t)DOUTC * NS * DH * 2);
    unsigned short* Mlo   = (unsigned short*)alloc((size_t)DOUTC * NS * DH * 2);
    float* bcomb    = (float*)alloc(DOUTC * 4);
    unsigned short* xb    = (unsigned short*)alloc((size_t)n * DIN * 2);
    unsigned short* z0    = (unsigned short*)alloc((size_t)n * DH * 2);
    unsigned short* h1cat = (unsigned short*)alloc((size_t)n * NS * DH * 2);
    unsigned short* g1cat = (unsigned short*)alloc((size_t)n * NS * DH * 2);
    unsigned short* q     = (unsigned short*)alloc((size_t)n * DOUTC * 2);

    hipMemsetAsync(counts, 0, (size_t)n * 4, stream);
    hipMemsetAsync(cursor, 0, (size_t)n * 4, stream);

    k_count_r<<<2048, 256, 0, stream>>>(dst, counts, e, n);
    k_dis<<<(n + 255) / 256, 256, 0, stream>>>(counts, dis, n);

    int nb = (n + 511) / 512;
    k_scanA<<<nb, 512, 0, stream>>>(counts, rowstart, bsums, n);
    k_scanB<<<1, 256, 0, stream>>>(bsums, nb);
    k_scanC<<<(n + 255) / 256, 256, 0, stream>>>(rowstart, bsums, n);
    k_fill_r<<<2048, 256, 0, stream>>>(src, dst, rowstart, cursor, col, e, n);

    k_prep_w<<<(NS * DH * DH + 255) / 256, 256, 0, stream>>>(
        W0, W1, W2, Wf, b2, bf, Wt0hi, Wt0lo, Wt1hi, Wt1lo, Mhi, Mlo, bcomb);
    k_cvt<<<2048, 256, 0, stream>>>((const float2*)x, (unsigned int*)xb, n * DIN / 2);

    // z0 = P(xb)  (shared across scales)
    k_agg128<<<1280, 256, 0, stream>>>((const unsigned int*)xb, (unsigned int*)z0,
                                       dis, rowstart, counts, col, n);
    const int GG = (n / 16 + 3) / 4;
    // h1cat[:, s*128:(s+1)*128] = LN(relu(z0 @ W0_s + b0_s)) for all s
    k_gemm0<<<GG, 256, 0, stream>>>(z0, Wt0hi, Wt0lo, b0, gamma, beta, h1cat, n);
    // g1cat = P(h1cat)  (batched 384-ch aggregation)
    k_agg384<<<1280, 256, 0, stream>>>((const unsigned int*)h1cat, (unsigned int*)g1cat,
                                       dis, rowstart, counts, col, n);
    // q = concat_s(LN(relu(g1cat_s @ W1_s + b1_s))) @ Mcat   (LDS-fused)
    k_gemm1q<<<GG, 256, 0, stream>>>(g1cat, Wt1hi, Wt1lo, Mhi, Mlo,
                                     b1, gamma, beta, q, n);
    // out = P(q) + bcomb
    k_agg64<<<1280, 256, 0, stream>>>((const unsigned int*)q, out, bcomb,
                                      dis, rowstart, counts, col, n);
}

// Round 5
// 1403.275 us; speedup vs baseline: 1.6616x; 1.0731x over previous
//
#include <hip/hip_runtime.h>

#define DIN 128
#define DH 128
#define DOUTC 64
#define NS 3
#define NL 3
#define EPSV 1e-5f

typedef __attribute__((ext_vector_type(8))) short bf16x8;
typedef __attribute__((ext_vector_type(4))) float f32x4;

static __device__ inline float bf2f(unsigned short h) {
    unsigned int u = ((unsigned int)h) << 16;
    return __builtin_bit_cast(float, u);
}
static __device__ inline unsigned short f2bf(float f) {
    unsigned int u = __builtin_bit_cast(unsigned int, f);
    u += 0x7fffu + ((u >> 16) & 1u);
    return (unsigned short)(u >> 16);
}
static __device__ inline float lo16(unsigned int u) {
    return __builtin_bit_cast(float, u << 16);
}
static __device__ inline float hi16(unsigned int u) {
    return __builtin_bit_cast(float, u & 0xffff0000u);
}

// ---------------- degree count, XCD-range-localized, int4 reads ----------------
__global__ __launch_bounds__(256) void k_count_r(const int* __restrict__ dst,
                                                 int* __restrict__ counts, int e, int n) {
    int rg = blockIdx.x & 7;
    int lo = rg * (n >> 3);
    int hi = (rg == 7) ? n : lo + (n >> 3);
    int nb = gridDim.x >> 3, bi = blockIdx.x >> 3;
    int e4 = e >> 2;
    const int4* dst4 = (const int4*)dst;
    for (int i = bi * 256 + threadIdx.x; i < e4; i += nb * 256) {
        int4 d = dst4[i];
        if (d.x >= lo && d.x < hi) atomicAdd(&counts[d.x], 1);
        if (d.y >= lo && d.y < hi) atomicAdd(&counts[d.y], 1);
        if (d.z >= lo && d.z < hi) atomicAdd(&counts[d.z], 1);
        if (d.w >= lo && d.w < hi) atomicAdd(&counts[d.w], 1);
    }
    if (bi == 0 && (int)threadIdx.x < (e & 3)) {
        int d = dst[e4 * 4 + threadIdx.x];
        if (d >= lo && d < hi) atomicAdd(&counts[d], 1);
    }
}

__global__ void k_dis(const int* __restrict__ counts, float* __restrict__ dis, int n) {
    int i = blockIdx.x * blockDim.x + threadIdx.x;
    if (i < n) dis[i] = rsqrtf((float)counts[i] + 1.0f);
}

// ---------------- exclusive scan (3-phase) ----------------
__global__ void k_scanA(const int* __restrict__ counts, int* __restrict__ row_start,
                        int* __restrict__ bsums, int n) {
    __shared__ int s[512];
    int t = threadIdx.x;
    int i = blockIdx.x * 512 + t;
    int v = (i < n) ? counts[i] : 0;
    s[t] = v;
    __syncthreads();
    for (int off = 1; off < 512; off <<= 1) {
        int x = s[t];
        if (t >= off) x += s[t - off];
        __syncthreads();
        s[t] = x;
        __syncthreads();
    }
    if (i < n) row_start[i] = s[t] - v;
    if (t == 511) bsums[blockIdx.x] = s[511];
}

__global__ void k_scanB(int* __restrict__ bsums, int nb) {
    __shared__ int s[256];
    int t = threadIdx.x;
    int v = (t < nb) ? bsums[t] : 0;
    s[t] = v;
    __syncthreads();
    for (int off = 1; off < 256; off <<= 1) {
        int x = s[t];
        if (t >= off) x += s[t - off];
        __syncthreads();
        s[t] = x;
        __syncthreads();
    }
    if (t < nb) bsums[t] = s[t] - v;
}

__global__ void k_scanC(int* __restrict__ row_start, const int* __restrict__ bsums, int n) {
    int i = blockIdx.x * blockDim.x + threadIdx.x;
    if (i < n) row_start[i] += bsums[i >> 9];
}

// ---------------- CSR fill: cursor pre-initialized to rowstart, single atomic ----------------
__global__ __launch_bounds__(256) void k_fill_r(const int* __restrict__ src,
                                                const int* __restrict__ dst,
                                                int* __restrict__ cursor,
                                                int* __restrict__ col, int e, int n) {
    int rg = blockIdx.x & 7;
    int lo = rg * (n >> 3);
    int hi = (rg == 7) ? n : lo + (n >> 3);
    int nb = gridDim.x >> 3, bi = blockIdx.x >> 3;
    int e4 = e >> 2;
    const int4* dst4 = (const int4*)dst;
    const int4* src4 = (const int4*)src;
    for (int i = bi * 256 + threadIdx.x; i < e4; i += nb * 256) {
        int4 d = dst4[i];
        int4 s = src4[i];
        if (d.x >= lo && d.x < hi) col[atomicAdd(&cursor[d.x], 1)] = s.x;
        if (d.y >= lo && d.y < hi) col[atomicAdd(&cursor[d.y], 1)] = s.y;
        if (d.z >= lo && d.z < hi) col[atomicAdd(&cursor[d.z], 1)] = s.z;
        if (d.w >= lo && d.w < hi) col[atomicAdd(&cursor[d.w], 1)] = s.w;
    }
    if (bi == 0 && (int)threadIdx.x < (e & 3)) {
        int d = dst[e4 * 4 + threadIdx.x];
        int s = src[e4 * 4 + threadIdx.x];
        if (d >= lo && d < hi) col[atomicAdd(&cursor[d], 1)] = s;
    }
}

// ---------------- weight prep: transpose + bf16 hi/lo split; Mcat; bcomb ----------------
__global__ void k_prep_w(const float* __restrict__ W0, const float* __restrict__ W1,
                         const float* __restrict__ W2, const float* __restrict__ Wf,
                         const float* __restrict__ b2, const float* __restrict__ bf,
                         unsigned short* __restrict__ Wt0hi, unsigned short* __restrict__ Wt0lo,
                         unsigned short* __restrict__ Wt1hi, unsigned short* __restrict__ Wt1lo,
                         unsigned short* __restrict__ Mhi, unsigned short* __restrict__ Mlo,
                         float* __restrict__ bcomb) {
    int idx = blockIdx.x * blockDim.x + threadIdx.x;
    if (idx < NS * DH * DH) {
        int s = idx / (DH * DH);
        int rem = idx % (DH * DH);
        int o = rem / DH, i = rem % DH;
        {
            float v = W0[(size_t)s * DH * DH + (size_t)i * DH + o];
            unsigned short h = f2bf(v);
            Wt0hi[idx] = h;
            Wt0lo[idx] = f2bf(v - bf2f(h));
        }
        {
            float v = W1[(size_t)s * DH * DH + (size_t)i * DH + o];
            unsigned short h = f2bf(v);
            Wt1hi[idx] = h;
            Wt1lo[idx] = f2bf(v - bf2f(h));
        }
    }
    if (idx < DOUTC * NS * DH) {   // o in [0,64), k in [0,384)
        int o = idx / (NS * DH);
        int k = idx % (NS * DH);
        int s = k / DH, i = k % DH;
        float acc = 0.f;
        for (int c = 0; c < DOUTC; ++c)
            acc += W2[((size_t)s * DH + i) * DOUTC + c] * Wf[((size_t)s * DOUTC + c) * DOUTC + o];
        unsigned short h = f2bf(acc);
        Mhi[idx] = h;
        Mlo[idx] = f2bf(acc - bf2f(h));
    }
    if (idx < DOUTC) {
        float acc = bf[idx];
        for (int s = 0; s < NS; ++s)
            for (int c = 0; c < DOUTC; ++c)
                acc += b2[s * DOUTC + c] * Wf[((size_t)s * DOUTC + c) * DOUTC + idx];
        bcomb[idx] = acc;
    }
}

// ---------------- x -> bf16, PRE-SCALED by dis[node] ----------------
__global__ void k_cvt(const float2* __restrict__ x, unsigned int* __restrict__ xb,
                      const float* __restrict__ dis, int m) {
    int i = blockIdx.x * blockDim.x + threadIdx.x;
    int stride = gridDim.x * blockDim.x;
    for (; i < m; i += stride) {
        float d = dis[i >> 6];
        float2 v = x[i];
        xb[i] = ((unsigned int)f2bf(v.y * d) << 16) | f2bf(v.x * d);
    }
}

// ---------------- CSR aggregation, 128ch: out = dv * (sum of pre-scaled rows + self) ----------------
__global__ __launch_bounds__(256) void k_agg128(
        const unsigned int* __restrict__ in, unsigned int* __restrict__ out,
        const float* __restrict__ dis, const int* __restrict__ rowstart,
        const int* __restrict__ counts, const int* __restrict__ col, int n) {
    int wid = (blockIdx.x * blockDim.x + threadIdx.x) >> 6;
    int lane = threadIdx.x & 63;
    int nw = (gridDim.x * blockDim.x) >> 6;
    for (int v = wid; v < n; v += nw) {
        float dv = dis[v];
        const int* colp = col + rowstart[v];
        int cnt = counts[v];
        unsigned int us = in[(size_t)v * 64 + lane];
        float a0 = lo16(us), a1 = hi16(us);
        int i = 0;
        for (; i + 4 <= cnt; i += 4) {
            int s0 = colp[i], s1 = colp[i + 1], s2 = colp[i + 2], s3 = colp[i + 3];
            unsigned int u0 = in[(size_t)s0 * 64 + lane];
            unsigned int u1 = in[(size_t)s1 * 64 + lane];
            unsigned int u2 = in[(size_t)s2 * 64 + lane];
            unsigned int u3 = in[(size_t)s3 * 64 + lane];
            a0 += lo16(u0); a1 += hi16(u0);
            a0 += lo16(u1); a1 += hi16(u1);
            a0 += lo16(u2); a1 += hi16(u2);
            a0 += lo16(u3); a1 += hi16(u3);
        }
        for (; i < cnt; ++i) {
            unsigned int u0 = in[(size_t)colp[i] * 64 + lane];
            a0 += lo16(u0); a1 += hi16(u0);
        }
        out[(size_t)v * 64 + lane] = ((unsigned int)f2bf(dv * a1) << 16) | f2bf(dv * a0);
    }
}

// ---------------- batched CSR aggregation, 384ch ----------------
__global__ __launch_bounds__(256) void k_agg384(
        const unsigned int* __restrict__ in, unsigned int* __restrict__ out,
        const float* __restrict__ dis, const int* __restrict__ rowstart,
        const int* __restrict__ counts, const int* __restrict__ col, int n) {
    int wid = (blockIdx.x * blockDim.x + threadIdx.x) >> 6;
    int lane = threadIdx.x & 63;
    int nw = (gridDim.x * blockDim.x) >> 6;
    for (int v = wid; v < n; v += nw) {
        float dv = dis[v];
        const int* colp = col + rowstart[v];
        int cnt = counts[v];
        const unsigned int* ps = in + (size_t)v * 192;
        unsigned int us0 = ps[lane], us1 = ps[lane + 64], us2 = ps[lane + 128];
        float a0 = lo16(us0), a1 = hi16(us0);
        float a2 = lo16(us1), a3 = hi16(us1);
        float a4 = lo16(us2), a5 = hi16(us2);
        int i = 0;
        for (; i + 4 <= cnt; i += 4) {
            int s0 = colp[i], s1 = colp[i + 1], s2 = colp[i + 2], s3 = colp[i + 3];
            const unsigned int* p0 = in + (size_t)s0 * 192;
            const unsigned int* p1 = in + (size_t)s1 * 192;
            const unsigned int* p2 = in + (size_t)s2 * 192;
            const unsigned int* p3 = in + (size_t)s3 * 192;
            unsigned int u00 = p0[lane], u01 = p0[lane + 64], u02 = p0[lane + 128];
            unsigned int u10 = p1[lane], u11 = p1[lane + 64], u12 = p1[lane + 128];
            unsigned int u20 = p2[lane], u21 = p2[lane + 64], u22 = p2[lane + 128];
            unsigned int u30 = p3[lane], u31 = p3[lane + 64], u32 = p3[lane + 128];
            a0 += lo16(u00); a1 += hi16(u00);
            a2 += lo16(u01); a3 += hi16(u01);
            a4 += lo16(u02); a5 += hi16(u02);
            a0 += lo16(u10); a1 += hi16(u10);
            a2 += lo16(u11); a3 += hi16(u11);
            a4 += lo16(u12); a5 += hi16(u12);
            a0 += lo16(u20); a1 += hi16(u20);
            a2 += lo16(u21); a3 += hi16(u21);
            a4 += lo16(u22); a5 += hi16(u22);
            a0 += lo16(u30); a1 += hi16(u30);
            a2 += lo16(u31); a3 += hi16(u31);
            a4 += lo16(u32); a5 += hi16(u32);
        }
        for (; i < cnt; ++i) {
            const unsigned int* p0 = in + (size_t)colp[i] * 192;
            unsigned int u00 = p0[lane], u01 = p0[lane + 64], u02 = p0[lane + 128];
            a0 += lo16(u00); a1 += hi16(u00);
            a2 += lo16(u01); a3 += hi16(u01);
            a4 += lo16(u02); a5 += hi16(u02);
        }
        unsigned int* po = out + (size_t)v * 192;
        po[lane]       = ((unsigned int)f2bf(dv * a1) << 16) | f2bf(dv * a0);
        po[lane + 64]  = ((unsigned int)f2bf(dv * a3) << 16) | f2bf(dv * a2);
        po[lane + 128] = ((unsigned int)f2bf(dv * a5) << 16) | f2bf(dv * a4);
    }
}

// ---------------- final aggregation, 64ch -> fp32 + bcomb ----------------
__global__ __launch_bounds__(256) void k_agg64(
        const unsigned int* __restrict__ in, float* __restrict__ out,
        const float* __restrict__ bcomb, const float* __restrict__ dis,
        const int* __restrict__ rowstart, const int* __restrict__ counts,
        const int* __restrict__ col, int n) {
    int wid = (blockIdx.x * blockDim.x + threadIdx.x) >> 6;
    int lane = threadIdx.x & 63;
    int half = lane >> 5, c = lane & 31;
    int nw = (gridDim.x * blockDim.x) >> 6;
    float bc0 = bcomb[c * 2], bc1 = bcomb[c * 2 + 1];
    for (int w = wid; w * 2 < n; w += nw) {
        int v = w * 2 + half;
        if (v >= n) continue;
        float dv = dis[v];
        const int* colp = col + rowstart[v];
        int cnt = counts[v];
        unsigned int us = in[(size_t)v * 32 + c];
        float a0 = lo16(us), a1 = hi16(us);
        int i = 0;
        for (; i + 4 <= cnt; i += 4) {
            int s0 = colp[i], s1 = colp[i + 1], s2 = colp[i + 2], s3 = colp[i + 3];
            unsigned int u0 = in[(size_t)s0 * 32 + c];
            unsigned int u1 = in[(size_t)s1 * 32 + c];
            unsigned int u2 = in[(size_t)s2 * 32 + c];
            unsigned int u3 = in[(size_t)s3 * 32 + c];
            a0 += lo16(u0); a1 += hi16(u0);
            a0 += lo16(u1); a1 += hi16(u1);
            a0 += lo16(u2); a1 += hi16(u2);
            a0 += lo16(u3); a1 += hi16(u3);
        }
        for (; i < cnt; ++i) {
            unsigned int u0 = in[(size_t)colp[i] * 32 + c];
            a0 += lo16(u0); a1 += hi16(u0);
        }
        float2 o = make_float2(dv * a0 + bc0, dv * a1 + bc1);
        *(float2*)&out[(size_t)v * 64 + c * 2] = o;
    }
}

// ---------------- fused layer-0 GEMM: z0 @ W0_s for s=0..2 -> h1cat [n][384], pre-scaled ----------------
__global__ __launch_bounds__(256) void k_gemm0(
        const unsigned short* __restrict__ A, const unsigned short* __restrict__ Whi,
        const unsigned short* __restrict__ Wlo, const float* __restrict__ bias,
        const float* __restrict__ gamma, const float* __restrict__ beta,
        const float* __restrict__ dis, unsigned short* __restrict__ out, int n) {
    int wave = threadIdx.x >> 6, lane = threadIdx.x & 63;
    int g = blockIdx.x * 4 + wave;
    if (g * 16 >= n) return;
    int r16 = lane & 15, g4 = lane >> 4;
    int row = g * 16 + r16;
    if (row >= n) row = n - 1;

    bf16x8 a[4];
    #pragma unroll
    for (int ks = 0; ks < 4; ++ks)
        a[ks] = *(const bf16x8*)&A[(size_t)row * DH + ks * 32 + g4 * 8];

    for (int s = 0; s < NS; ++s) {
        const unsigned short* whi = Whi + (size_t)s * DH * DH;
        const unsigned short* wlo = Wlo + (size_t)s * DH * DH;
        f32x4 acc[8];
        #pragma unroll
        for (int t = 0; t < 8; ++t) acc[t] = (f32x4){0.f, 0.f, 0.f, 0.f};
        #pragma unroll
        for (int ks = 0; ks < 4; ++ks) {
            #pragma unroll
            for (int t = 0; t < 8; ++t) {
                size_t wofs = (size_t)(t * 16 + r16) * DH + ks * 32 + g4 * 8;
                bf16x8 bh = *(const bf16x8*)&whi[wofs];
                bf16x8 bl = *(const bf16x8*)&wlo[wofs];
                acc[t] = __builtin_amdgcn_mfma_f32_16x16x32_bf16(a[ks], bh, acc[t], 0, 0, 0);
                acc[t] = __builtin_amdgcn_mfma_f32_16x16x32_bf16(a[ks], bl, acc[t], 0, 0, 0);
            }
        }
        float bia[8], gam[8], bet[8];
        #pragma unroll
        for (int t = 0; t < 8; ++t) {
            bia[t] = bias[s * DH + t * 16 + r16];
            gam[t] = gamma[(size_t)(s * NL + 0) * DH + t * 16 + r16];
            bet[t] = beta[(size_t)(s * NL + 0) * DH + t * 16 + r16];
        }
        #pragma unroll
        for (int r = 0; r < 4; ++r) {
            float y[8];
            float sm = 0.f, q = 0.f;
            #pragma unroll
            for (int t = 0; t < 8; ++t) {
                y[t] = fmaxf(acc[t][r] + bia[t], 0.f);
                sm += y[t];
                q += y[t] * y[t];
            }
            #pragma unroll
            for (int off = 8; off; off >>= 1) {
                sm += __shfl_xor(sm, off);
                q += __shfl_xor(q, off);
            }
            float mu = sm * (1.f / 128.f);
            float var = q * (1.f / 128.f) - mu * mu;
            float rstd = rsqrtf(var + EPSV);
            int node = g * 16 + g4 * 4 + r;
            if (node < n) {
                float dnode = dis[node];
                #pragma unroll
                for (int t = 0; t < 8; ++t) {
                    float o = ((y[t] - mu) * rstd * gam[t] + bet[t]) * dnode;
                    out[(size_t)node * (NS * DH) + s * DH + t * 16 + r16] = f2bf(o);
                }
            }
        }
    }
}

// ---------------- fused layer-1 GEMM + folded final GEMM, q pre-scaled ----------------
__global__ __launch_bounds__(256) void k_gemm1q(
        const unsigned short* __restrict__ G, const unsigned short* __restrict__ Whi,
        const unsigned short* __restrict__ Wlo, const unsigned short* __restrict__ Mhi,
        const unsigned short* __restrict__ Mlo, const float* __restrict__ bias,
        const float* __restrict__ gamma, const float* __restrict__ beta,
        const float* __restrict__ dis, unsigned short* __restrict__ q, int n) {
    __shared__ __align__(16) unsigned short sH[4][16][392];
    int wave = threadIdx.x >> 6, lane = threadIdx.x & 63;
    int g = blockIdx.x * 4 + wave;
    if (g * 16 >= n) return;
    int r16 = lane & 15, g4 = lane >> 4;
    int row = g * 16 + r16;
    if (row >= n) row = n - 1;

    for (int s = 0; s < NS; ++s) {
        bf16x8 a[4];
        #pragma unroll
        for (int ks = 0; ks < 4; ++ks)
            a[ks] = *(const bf16x8*)&G[(size_t)row * (NS * DH) + s * DH + ks * 32 + g4 * 8];
        const unsigned short* whi = Whi + (size_t)s * DH * DH;
        const unsigned short* wlo = Wlo + (size_t)s * DH * DH;
        f32x4 acc[8];
        #pragma unroll
        for (int t = 0; t < 8; ++t) acc[t] = (f32x4){0.f, 0.f, 0.f, 0.f};
        #pragma unroll
        for (int ks = 0; ks < 4; ++ks) {
            #pragma unroll
            for (int t = 0; t < 8; ++t) {
                size_t wofs = (size_t)(t * 16 + r16) * DH + ks * 32 + g4 * 8;
                bf16x8 bh = *(const bf16x8*)&whi[wofs];
                bf16x8 bl = *(const bf16x8*)&wlo[wofs];
                acc[t] = __builtin_amdgcn_mfma_f32_16x16x32_bf16(a[ks], bh, acc[t], 0, 0, 0);
                acc[t] = __builtin_amdgcn_mfma_f32_16x16x32_bf16(a[ks], bl, acc[t], 0, 0, 0);
            }
        }
        float bia[8], gam[8], bet[8];
        #pragma unroll
        for (int t = 0; t < 8; ++t) {
            bia[t] = bias[s * DH + t * 16 + r16];
            gam[t] = gamma[(size_t)(s * NL + 1) * DH + t * 16 + r16];
            bet[t] = beta[(size_t)(s * NL + 1) * DH + t * 16 + r16];
        }
        #pragma unroll
        for (int r = 0; r < 4; ++r) {
            float y[8];
            float sm = 0.f, qq = 0.f;
            #pragma unroll
            for (int t = 0; t < 8; ++t) {
                y[t] = fmaxf(acc[t][r] + bia[t], 0.f);
                sm += y[t];
                qq += y[t] * y[t];
            }
            #pragma unroll
            for (int off = 8; off; off >>= 1) {
                sm += __shfl_xor(sm, off);
                qq += __shfl_xor(qq, off);
            }
            float mu = sm * (1.f / 128.f);
            float var = qq * (1.f / 128.f) - mu * mu;
            float rstd = rsqrtf(var + EPSV);
            #pragma unroll
            for (int t = 0; t < 8; ++t) {
                float o = (y[t] - mu) * rstd * gam[t] + bet[t];
                sH[wave][g4 * 4 + r][s * DH + t * 16 + r16] = f2bf(o);
            }
        }
    }
    __syncthreads();
    // q-GEMM: [16][384] @ Mcat^T[64][384]
    f32x4 qa[4];
    #pragma unroll
    for (int t = 0; t < 4; ++t) qa[t] = (f32x4){0.f, 0.f, 0.f, 0.f};
    #pragma unroll
    for (int ks = 0; ks < 12; ++ks) {
        bf16x8 av = *(const bf16x8*)&sH[wave][r16][ks * 32 + g4 * 8];
        #pragma unroll
        for (int t = 0; t < 4; ++t) {
            size_t wofs = (size_t)(t * 16 + r16) * (NS * DH) + ks * 32 + g4 * 8;
            bf16x8 bh = *(const bf16x8*)&Mhi[wofs];
            bf16x8 bl = *(const bf16x8*)&Mlo[wofs];
            qa[t] = __builtin_amdgcn_mfma_f32_16x16x32_bf16(av, bh, qa[t], 0, 0, 0);
            qa[t] = __builtin_amdgcn_mfma_f32_16x16x32_bf16(av, bl, qa[t], 0, 0, 0);
        }
    }
    #pragma unroll
    for (int r = 0; r < 4; ++r) {
        int node = g * 16 + g4 * 4 + r;
        if (node < n) {
            float dnode = dis[node];
            #pragma unroll
            for (int t = 0; t < 4; ++t)
                q[(size_t)node * DOUTC + t * 16 + r16] = f2bf(qa[t][r] * dnode);
        }
    }
}

extern "C" void kernel_launch(void* const* d_in, const int* in_sizes, int n_in,
                              void* d_out, int out_size, void* d_ws, size_t ws_size,
                              hipStream_t stream) {
    const float* x    = (const float*)d_in[0];
    const int*   ei   = (const int*)d_in[1];
    const float* W0   = (const float*)d_in[2];
    const float* b0   = (const float*)d_in[3];
    const float* W1   = (const float*)d_in[4];
    const float* b1   = (const float*)d_in[5];
    const float* W2   = (const float*)d_in[6];
    const float* b2   = (const float*)d_in[7];
    const float* gamma= (const float*)d_in[8];
    const float* beta = (const float*)d_in[9];
    const float* Wf   = (const float*)d_in[10];
    const float* bf   = (const float*)d_in[11];
    float* out = (float*)d_out;

    const int n = in_sizes[0] / DIN;
    const int e = in_sizes[1] / 2;
    const int* src = ei;
    const int* dst = ei + e;

    char* ws = (char*)d_ws;
    auto alloc = [&](size_t bytes) {
        char* p = ws;
        ws += (bytes + 255) & ~(size_t)255;
        return p;
    };
    int*   counts   = (int*)alloc((size_t)n * 4);
    int*   cursor   = (int*)alloc((size_t)n * 4);
    int*   rowstart = (int*)alloc((size_t)n * 4);
    int*   bsums    = (int*)alloc(4096);
    float* dis      = (float*)alloc((size_t)n * 4);
    int*   col      = (int*)alloc((size_t)e * 4);
    unsigned short* Wt0hi = (unsigned short*)alloc((size_t)NS * DH * DH * 2);
    unsigned short* Wt0lo = (unsigned short*)alloc((size_t)NS * DH * DH * 2);
    unsigned short* Wt1hi = (unsigned short*)alloc((size_t)NS * DH * DH * 2);
    unsigned short* Wt1lo = (unsigned short*)alloc((size_t)NS * DH * DH * 2);
    unsigned short* Mhi   = (unsigned short*)alloc((size_t)DOUTC * NS * DH * 2);
    unsigned short* Mlo   = (unsigned short*)alloc((size_t)DOUTC * NS * DH * 2);
    float* bcomb    = (float*)alloc(DOUTC * 4);
    unsigned short* xb    = (unsigned short*)alloc((size_t)n * DIN * 2);
    unsigned short* z0    = (unsigned short*)alloc((size_t)n * DH * 2);
    unsigned short* h1cat = (unsigned short*)alloc((size_t)n * NS * DH * 2);
    unsigned short* g1cat = (unsigned short*)alloc((size_t)n * NS * DH * 2);
    unsigned short* q     = (unsigned short*)alloc((size_t)n * DOUTC * 2);

    hipMemsetAsync(counts, 0, (size_t)n * 4, stream);

    k_count_r<<<2048, 256, 0, stream>>>(dst, counts, e, n);
    k_dis<<<(n + 255) / 256, 256, 0, stream>>>(counts, dis, n);

    int nb = (n + 511) / 512;
    k_scanA<<<nb, 512, 0, stream>>>(counts, rowstart, bsums, n);
    k_scanB<<<1, 256, 0, stream>>>(bsums, nb);
    k_scanC<<<(n + 255) / 256, 256, 0, stream>>>(rowstart, bsums, n);
    hipMemcpyAsync(cursor, rowstart, (size_t)n * 4, hipMemcpyDeviceToDevice, stream);
    k_fill_r<<<2048, 256, 0, stream>>>(src, dst, cursor, col, e, n);

    k_prep_w<<<(NS * DH * DH + 255) / 256, 256, 0, stream>>>(
        W0, W1, W2, Wf, b2, bf, Wt0hi, Wt0lo, Wt1hi, Wt1lo, Mhi, Mlo, bcomb);
    k_cvt<<<2048, 256, 0, stream>>>((const float2*)x, (unsigned int*)xb, dis, n * DIN / 2);

    // z0 = P(x)  (shared across scales; xb pre-scaled, agg multiplies by dv)
    k_agg128<<<2048, 256, 0, stream>>>((const unsigned int*)xb, (unsigned int*)z0,
                                       dis, rowstart, counts, col, n);
    const int GG = (n / 16 + 3) / 4;
    // h1cat[:, s*128:(s+1)*128] = dis * LN(relu(z0 @ W0_s + b0_s)) for all s
    k_gemm0<<<GG, 256, 0, stream>>>(z0, Wt0hi, Wt0lo, b0, gamma, beta, dis, h1cat, n);
    // g1cat = P(h1)  (batched 384-ch aggregation)
    k_agg384<<<2048, 256, 0, stream>>>((const unsigned int*)h1cat, (unsigned int*)g1cat,
                                       dis, rowstart, counts, col, n);
    // q = dis * concat_s(LN(relu(g1cat_s @ W1_s + b1_s))) @ Mcat   (LDS-fused)
    k_gemm1q<<<GG, 256, 0, stream>>>(g1cat, Wt1hi, Wt1lo, Mhi, Mlo,
                                     b1, gamma, beta, dis, q, n);
    // out = P(q) + bcomb
    k_agg64<<<2048, 256, 0, stream>>>((const unsigned int*)q, out, bcomb,
                                      dis, rowstart, counts, col, n);
}

// Round 6
// 1241.662 us; speedup vs baseline: 1.8779x; 1.1302x over previous
//
#include <hip/hip_runtime.h>

#define DIN 128
#define DH 128
#define DOUTC 64
#define NS 3
#define NL 3
#define EPSV 1e-5f

typedef __attribute__((ext_vector_type(8))) short bf16x8;
typedef __attribute__((ext_vector_type(4))) float f32x4;

static __device__ inline float bf2f(unsigned short h) {
    unsigned int u = ((unsigned int)h) << 16;
    return __builtin_bit_cast(float, u);
}
static __device__ inline unsigned short f2bf(float f) {
    unsigned int u = __builtin_bit_cast(unsigned int, f);
    u += 0x7fffu + ((u >> 16) & 1u);
    return (unsigned short)(u >> 16);
}
static __device__ inline float lo16(unsigned int u) {
    return __builtin_bit_cast(float, u << 16);
}
static __device__ inline float hi16(unsigned int u) {
    return __builtin_bit_cast(float, u & 0xffff0000u);
}
static __device__ inline unsigned int pkbf(float lo, float hi) {
    return ((unsigned int)f2bf(hi) << 16) | f2bf(lo);
}
static __device__ inline float sext8(unsigned int u, int k) {
    return (float)((int)(u << (24 - 8 * k)) >> 24);
}
static __device__ inline unsigned int pk8(float a, float b, float c, float d, float qs) {
    int q0 = (int)rintf(a * qs), q1 = (int)rintf(b * qs);
    int q2 = (int)rintf(c * qs), q3 = (int)rintf(d * qs);
    return (q0 & 255) | ((q1 & 255) << 8) | ((q2 & 255) << 16) | ((q3 & 255) << 24);
}

// ---------------- degree count, XCD-range-localized ----------------
__global__ __launch_bounds__(256) void k_count_r(const int* __restrict__ dst,
                                                 int* __restrict__ counts, int e, int n) {
    int rg = blockIdx.x & 7;
    int lo = rg * (n >> 3);
    int hi = (rg == 7) ? n : lo + (n >> 3);
    int nb = gridDim.x >> 3, bi = blockIdx.x >> 3;
    int e4 = e >> 2;
    const int4* dst4 = (const int4*)dst;
    for (int i = bi * 256 + threadIdx.x; i < e4; i += nb * 256) {
        int4 d = dst4[i];
        if (d.x >= lo && d.x < hi) atomicAdd(&counts[d.x], 1);
        if (d.y >= lo && d.y < hi) atomicAdd(&counts[d.y], 1);
        if (d.z >= lo && d.z < hi) atomicAdd(&counts[d.z], 1);
        if (d.w >= lo && d.w < hi) atomicAdd(&counts[d.w], 1);
    }
    if (bi == 0 && (int)threadIdx.x < (e & 3)) {
        int d = dst[e4 * 4 + threadIdx.x];
        if (d >= lo && d < hi) atomicAdd(&counts[d], 1);
    }
}

__global__ void k_dis(const int* __restrict__ counts, float* __restrict__ dis, int n) {
    int i = blockIdx.x * blockDim.x + threadIdx.x;
    if (i < n) dis[i] = rsqrtf((float)counts[i] + 1.0f);
}

// ---------------- exclusive scan (3-phase) ----------------
__global__ void k_scanA(const int* __restrict__ counts, int* __restrict__ row_start,
                        int* __restrict__ bsums, int n) {
    __shared__ int s[512];
    int t = threadIdx.x;
    int i = blockIdx.x * 512 + t;
    int v = (i < n) ? counts[i] : 0;
    s[t] = v;
    __syncthreads();
    for (int off = 1; off < 512; off <<= 1) {
        int x = s[t];
        if (t >= off) x += s[t - off];
        __syncthreads();
        s[t] = x;
        __syncthreads();
    }
    if (i < n) row_start[i] = s[t] - v;
    if (t == 511) bsums[blockIdx.x] = s[511];
}

__global__ void k_scanB(int* __restrict__ bsums, int nb) {
    __shared__ int s[256];
    int t = threadIdx.x;
    int v = (t < nb) ? bsums[t] : 0;
    s[t] = v;
    __syncthreads();
    for (int off = 1; off < 256; off <<= 1) {
        int x = s[t];
        if (t >= off) x += s[t - off];
        __syncthreads();
        s[t] = x;
        __syncthreads();
    }
    if (t < nb) bsums[t] = s[t] - v;
}

__global__ void k_scanC(int* __restrict__ row_start, const int* __restrict__ bsums, int n) {
    int i = blockIdx.x * blockDim.x + threadIdx.x;
    if (i < n) row_start[i] += bsums[i >> 9];
}

// ---------------- CSR fill ----------------
__global__ __launch_bounds__(256) void k_fill_r(const int* __restrict__ src,
                                                const int* __restrict__ dst,
                                                int* __restrict__ cursor,
                                                int* __restrict__ col, int e, int n) {
    int rg = blockIdx.x & 7;
    int lo = rg * (n >> 3);
    int hi = (rg == 7) ? n : lo + (n >> 3);
    int nb = gridDim.x >> 3, bi = blockIdx.x >> 3;
    int e4 = e >> 2;
    const int4* dst4 = (const int4*)dst;
    const int4* src4 = (const int4*)src;
    for (int i = bi * 256 + threadIdx.x; i < e4; i += nb * 256) {
        int4 d = dst4[i];
        int4 s = src4[i];
        if (d.x >= lo && d.x < hi) col[atomicAdd(&cursor[d.x], 1)] = s.x;
        if (d.y >= lo && d.y < hi) col[atomicAdd(&cursor[d.y], 1)] = s.y;
        if (d.z >= lo && d.z < hi) col[atomicAdd(&cursor[d.z], 1)] = s.z;
        if (d.w >= lo && d.w < hi) col[atomicAdd(&cursor[d.w], 1)] = s.w;
    }
    if (bi == 0 && (int)threadIdx.x < (e & 3)) {
        int d = dst[e4 * 4 + threadIdx.x];
        int s = src[e4 * 4 + threadIdx.x];
        if (d >= lo && d < hi) col[atomicAdd(&cursor[d], 1)] = s;
    }
}

// ---------------- weight prep ----------------
__global__ void k_prep_w(const float* __restrict__ W0, const float* __restrict__ W1,
                         const float* __restrict__ W2, const float* __restrict__ Wf,
                         const float* __restrict__ b2, const float* __restrict__ bf,
                         unsigned short* __restrict__ Wt0hi, unsigned short* __restrict__ Wt0lo,
                         unsigned short* __restrict__ Wt1hi, unsigned short* __restrict__ Wt1lo,
                         unsigned short* __restrict__ Mhi, unsigned short* __restrict__ Mlo,
                         float* __restrict__ bcomb) {
    int idx = blockIdx.x * blockDim.x + threadIdx.x;
    if (idx < NS * DH * DH) {
        int s = idx / (DH * DH);
        int rem = idx % (DH * DH);
        int o = rem / DH, i = rem % DH;
        {
            float v = W0[(size_t)s * DH * DH + (size_t)i * DH + o];
            unsigned short h = f2bf(v);
            Wt0hi[idx] = h;
            Wt0lo[idx] = f2bf(v - bf2f(h));
        }
        {
            float v = W1[(size_t)s * DH * DH + (size_t)i * DH + o];
            unsigned short h = f2bf(v);
            Wt1hi[idx] = h;
            Wt1lo[idx] = f2bf(v - bf2f(h));
        }
    }
    if (idx < DOUTC * NS * DH) {
        int o = idx / (NS * DH);
        int k = idx % (NS * DH);
        int s = k / DH, i = k % DH;
        float acc = 0.f;
        for (int c = 0; c < DOUTC; ++c)
            acc += W2[((size_t)s * DH + i) * DOUTC + c] * Wf[((size_t)s * DOUTC + c) * DOUTC + o];
        unsigned short h = f2bf(acc);
        Mhi[idx] = h;
        Mlo[idx] = f2bf(acc - bf2f(h));
    }
    if (idx < DOUTC) {
        float acc = bf[idx];
        for (int s = 0; s < NS; ++s)
            for (int c = 0; c < DOUTC; ++c)
                acc += b2[s * DOUTC + c] * Wf[((size_t)s * DOUTC + c) * DOUTC + idx];
        bcomb[idx] = acc;
    }
}

// ---------------- x fp32 -> int8 rows (scale absorbs dis) ----------------
// one wave per node; lane holds ch {2l, 2l+1}
__global__ __launch_bounds__(256) void k_cvtq(const float2* __restrict__ x,
                                              unsigned int* __restrict__ xq,
                                              float* __restrict__ xs,
                                              const float* __restrict__ dis, int n) {
    int wid = ((blockIdx.x * blockDim.x + threadIdx.x) >> 6);
    int lane = threadIdx.x & 63;
    if (wid >= n) return;
    float2 v = x[(size_t)wid * 64 + lane];
    float m = fmaxf(fabsf(v.x), fabsf(v.y));
    #pragma unroll
    for (int off = 32; off; off >>= 1) m = fmaxf(m, __shfl_xor(m, off));
    float qs = m > 0.f ? 127.f / m : 0.f;
    int q0 = (int)rintf(v.x * qs), q1 = (int)rintf(v.y * qs);
    ((unsigned short*)xq)[(size_t)wid * 64 + lane] =
        (unsigned short)((q0 & 255) | ((q1 & 255) << 8));
    if (lane == 0) xs[wid] = dis[wid] * m * (1.f / 127.f);
}

// ---------------- bf16 [n][384] -> int8 rows ----------------
// wave = 2 nodes; lane: half=l>>5, c=l&31; packed u32 j holds ch {4j..4j+3}
__global__ __launch_bounds__(256) void k_quant384(const unsigned int* __restrict__ h,
                                                  unsigned int* __restrict__ hq,
                                                  float* __restrict__ hs, int n) {
    int wid = ((blockIdx.x * blockDim.x + threadIdx.x) >> 6);
    int lane = threadIdx.x & 63;
    int half = lane >> 5, c = lane & 31;
    int v = wid * 2 + half;
    if (v >= n) return;
    const uint2* p = (const uint2*)(h + (size_t)v * 192);
    uint2 w0 = p[c], w1 = p[c + 32], w2 = p[c + 64];
    float f[12] = {lo16(w0.x), hi16(w0.x), lo16(w0.y), hi16(w0.y),
                   lo16(w1.x), hi16(w1.x), lo16(w1.y), hi16(w1.y),
                   lo16(w2.x), hi16(w2.x), lo16(w2.y), hi16(w2.y)};
    float m = 0.f;
    #pragma unroll
    for (int k = 0; k < 12; ++k) m = fmaxf(m, fabsf(f[k]));
    #pragma unroll
    for (int off = 16; off; off >>= 1) m = fmaxf(m, __shfl_xor(m, off));
    float qs = m > 0.f ? 127.f / m : 0.f;
    unsigned int* po = hq + (size_t)v * 96;
    po[c]      = pk8(f[0], f[1], f[2], f[3], qs);
    po[c + 32] = pk8(f[4], f[5], f[6], f[7], qs);
    po[c + 64] = pk8(f[8], f[9], f[10], f[11], qs);
    if (c == 0) hs[v] = m * (1.f / 127.f);
}

// ---------------- bf16 [n][64] -> int8 rows ----------------
// wave = 4 nodes; g=l>>4, c=l&15
__global__ __launch_bounds__(256) void k_quant64(const unsigned int* __restrict__ qb,
                                                 unsigned int* __restrict__ qq,
                                                 float* __restrict__ qs2, int n) {
    int wid = ((blockIdx.x * blockDim.x + threadIdx.x) >> 6);
    int lane = threadIdx.x & 63;
    int g = lane >> 4, c = lane & 15;
    int v = wid * 4 + g;
    if (v >= n) return;
    uint2 w = ((const uint2*)(qb + (size_t)v * 32))[c];
    float f0 = lo16(w.x), f1 = hi16(w.x), f2 = lo16(w.y), f3 = hi16(w.y);
    float m = fmaxf(fmaxf(fabsf(f0), fabsf(f1)), fmaxf(fabsf(f2), fabsf(f3)));
    #pragma unroll
    for (int off = 8; off; off >>= 1) m = fmaxf(m, __shfl_xor(m, off));
    float qs = m > 0.f ? 127.f / m : 0.f;
    qq[(size_t)v * 16 + c] = pk8(f0, f1, f2, f3, qs);
    if (c == 0) qs2[v] = m * (1.f / 127.f);
}

// ---------------- int8 CSR aggregation, 128ch -> z0 bf16 ----------------
// wave = 2 nodes; per lane 1 u32 (4 ch)
__global__ __launch_bounds__(256) void k_agg128q(
        const unsigned int* __restrict__ xq, const float* __restrict__ xs,
        unsigned int* __restrict__ z0, const float* __restrict__ dis,
        const int* __restrict__ rowstart, const int* __restrict__ counts,
        const int* __restrict__ col, int n) {
    int wid = (blockIdx.x * blockDim.x + threadIdx.x) >> 6;
    int lane = threadIdx.x & 63;
    int half = lane >> 5, c = lane & 31;
    int nw = (gridDim.x * blockDim.x) >> 6;
    int ntask = (n + 1) >> 1;
    for (int w = wid; w < ntask; w += nw) {
        int v = w * 2 + half;
        int vc = v < n ? v : n - 1;
        float dv = dis[vc];
        const int* colp = col + rowstart[vc];
        int cnt = v < n ? counts[vc] : 0;
        unsigned int us = xq[(size_t)vc * 32 + c];
        float sv = xs[vc];
        float a0 = sv * sext8(us, 0), a1 = sv * sext8(us, 1);
        float a2 = sv * sext8(us, 2), a3 = sv * sext8(us, 3);
        int i = 0;
        for (; i + 8 <= cnt; i += 8) {
            #pragma unroll
            for (int k = 0; k < 8; ++k) {
                int s0 = colp[i + k];
                float sc = xs[s0];
                unsigned int u = xq[(size_t)s0 * 32 + c];
                a0 += sc * sext8(u, 0); a1 += sc * sext8(u, 1);
                a2 += sc * sext8(u, 2); a3 += sc * sext8(u, 3);
            }
        }
        for (; i < cnt; ++i) {
            int s0 = colp[i];
            float sc = xs[s0];
            unsigned int u = xq[(size_t)s0 * 32 + c];
            a0 += sc * sext8(u, 0); a1 += sc * sext8(u, 1);
            a2 += sc * sext8(u, 2); a3 += sc * sext8(u, 3);
        }
        if (v < n) {
            uint2 o = {pkbf(dv * a0, dv * a1), pkbf(dv * a2, dv * a3)};
            *(uint2*)&z0[(size_t)v * 64 + 2 * c] = o;
        }
    }
}

// ---------------- int8 CSR aggregation, 384ch -> g1cat bf16 ----------------
// wave = 2 nodes; per lane 3 u32 (12 ch)
__global__ __launch_bounds__(256) void k_agg384q(
        const unsigned int* __restrict__ hq, const float* __restrict__ hs,
        unsigned int* __restrict__ g1, const float* __restrict__ dis,
        const int* __restrict__ rowstart, const int* __restrict__ counts,
        const int* __restrict__ col, int n) {
    int wid = (blockIdx.x * blockDim.x + threadIdx.x) >> 6;
    int lane = threadIdx.x & 63;
    int half = lane >> 5, c = lane & 31;
    int nw = (gridDim.x * blockDim.x) >> 6;
    int ntask = (n + 1) >> 1;
    for (int w = wid; w < ntask; w += nw) {
        int v = w * 2 + half;
        int vc = v < n ? v : n - 1;
        float dv = dis[vc];
        const int* colp = col + rowstart[vc];
        int cnt = v < n ? counts[vc] : 0;
        const unsigned int* rp = hq + (size_t)vc * 96;
        unsigned int u0 = rp[c], u1 = rp[c + 32], u2 = rp[c + 64];
        float sv = hs[vc];
        float a[12];
        #pragma unroll
        for (int k = 0; k < 4; ++k) {
            a[k]     = sv * sext8(u0, k);
            a[4 + k] = sv * sext8(u1, k);
            a[8 + k] = sv * sext8(u2, k);
        }
        int i = 0;
        for (; i + 4 <= cnt; i += 4) {
            #pragma unroll
            for (int k4 = 0; k4 < 4; ++k4) {
                int s0 = colp[i + k4];
                float sc = hs[s0];
                const unsigned int* p0 = hq + (size_t)s0 * 96;
                unsigned int w0 = p0[c], w1 = p0[c + 32], w2 = p0[c + 64];
                #pragma unroll
                for (int k = 0; k < 4; ++k) {
                    a[k]     += sc * sext8(w0, k);
                    a[4 + k] += sc * sext8(w1, k);
                    a[8 + k] += sc * sext8(w2, k);
                }
            }
        }
        for (; i < cnt; ++i) {
            int s0 = colp[i];
            float sc = hs[s0];
            const unsigned int* p0 = hq + (size_t)s0 * 96;
            unsigned int w0 = p0[c], w1 = p0[c + 32], w2 = p0[c + 64];
            #pragma unroll
            for (int k = 0; k < 4; ++k) {
                a[k]     += sc * sext8(w0, k);
                a[4 + k] += sc * sext8(w1, k);
                a[8 + k] += sc * sext8(w2, k);
            }
        }
        if (v < n) {
            unsigned int* po = g1 + (size_t)v * 192;
            uint2 o0 = {pkbf(dv * a[0], dv * a[1]), pkbf(dv * a[2], dv * a[3])};
            *(uint2*)&po[2 * c] = o0;
            uint2 o1 = {pkbf(dv * a[4], dv * a[5]), pkbf(dv * a[6], dv * a[7])};
            *(uint2*)&po[2 * c + 64] = o1;
            uint2 o2 = {pkbf(dv * a[8], dv * a[9]), pkbf(dv * a[10], dv * a[11])};
            *(uint2*)&po[2 * c + 128] = o2;
        }
    }
}

// ---------------- int8 CSR aggregation, 64ch -> out fp32 + bcomb ----------------
// wave = 4 nodes; per lane 1 u32 (4 ch)
__global__ __launch_bounds__(256) void k_agg64q(
        const unsigned int* __restrict__ qq, const float* __restrict__ qs2,
        float* __restrict__ out, const float* __restrict__ bcomb,
        const float* __restrict__ dis, const int* __restrict__ rowstart,
        const int* __restrict__ counts, const int* __restrict__ col, int n) {
    int wid = (blockIdx.x * blockDim.x + threadIdx.x) >> 6;
    int lane = threadIdx.x & 63;
    int g = lane >> 4, c = lane & 15;
    int nw = (gridDim.x * blockDim.x) >> 6;
    int ntask = (n + 3) >> 2;
    float4 bc = ((const float4*)bcomb)[c];
    for (int w = wid; w < ntask; w += nw) {
        int v = w * 4 + g;
        int vc = v < n ? v : n - 1;
        float dv = dis[vc];
        const int* colp = col + rowstart[vc];
        int cnt = v < n ? counts[vc] : 0;
        unsigned int us = qq[(size_t)vc * 16 + c];
        float sv = qs2[vc];
        float a0 = sv * sext8(us, 0), a1 = sv * sext8(us, 1);
        float a2 = sv * sext8(us, 2), a3 = sv * sext8(us, 3);
        int i = 0;
        for (; i + 8 <= cnt; i += 8) {
            #pragma unroll
            for (int k = 0; k < 8; ++k) {
                int s0 = colp[i + k];
                float sc = qs2[s0];
                unsigned int u = qq[(size_t)s0 * 16 + c];
                a0 += sc * sext8(u, 0); a1 += sc * sext8(u, 1);
                a2 += sc * sext8(u, 2); a3 += sc * sext8(u, 3);
            }
        }
        for (; i < cnt; ++i) {
            int s0 = colp[i];
            float sc = qs2[s0];
            unsigned int u = qq[(size_t)s0 * 16 + c];
            a0 += sc * sext8(u, 0); a1 += sc * sext8(u, 1);
            a2 += sc * sext8(u, 2); a3 += sc * sext8(u, 3);
        }
        if (v < n) {
            float4 o = make_float4(dv * a0 + bc.x, dv * a1 + bc.y,
                                   dv * a2 + bc.z, dv * a3 + bc.w);
            *(float4*)&out[(size_t)v * 64 + 4 * c] = o;
        }
    }
}

// ---------------- fused layer-0 GEMM (unchanged) ----------------
__global__ __launch_bounds__(256) void k_gemm0(
        const unsigned short* __restrict__ A, const unsigned short* __restrict__ Whi,
        const unsigned short* __restrict__ Wlo, const float* __restrict__ bias,
        const float* __restrict__ gamma, const float* __restrict__ beta,
        const float* __restrict__ dis, unsigned short* __restrict__ out, int n) {
    int wave = threadIdx.x >> 6, lane = threadIdx.x & 63;
    int g = blockIdx.x * 4 + wave;
    if (g * 16 >= n) return;
    int r16 = lane & 15, g4 = lane >> 4;
    int row = g * 16 + r16;
    if (row >= n) row = n - 1;

    bf16x8 a[4];
    #pragma unroll
    for (int ks = 0; ks < 4; ++ks)
        a[ks] = *(const bf16x8*)&A[(size_t)row * DH + ks * 32 + g4 * 8];

    for (int s = 0; s < NS; ++s) {
        const unsigned short* whi = Whi + (size_t)s * DH * DH;
        const unsigned short* wlo = Wlo + (size_t)s * DH * DH;
        f32x4 acc[8];
        #pragma unroll
        for (int t = 0; t < 8; ++t) acc[t] = (f32x4){0.f, 0.f, 0.f, 0.f};
        #pragma unroll
        for (int ks = 0; ks < 4; ++ks) {
            #pragma unroll
            for (int t = 0; t < 8; ++t) {
                size_t wofs = (size_t)(t * 16 + r16) * DH + ks * 32 + g4 * 8;
                bf16x8 bh = *(const bf16x8*)&whi[wofs];
                bf16x8 bl = *(const bf16x8*)&wlo[wofs];
                acc[t] = __builtin_amdgcn_mfma_f32_16x16x32_bf16(a[ks], bh, acc[t], 0, 0, 0);
                acc[t] = __builtin_amdgcn_mfma_f32_16x16x32_bf16(a[ks], bl, acc[t], 0, 0, 0);
            }
        }
        float bia[8], gam[8], bet[8];
        #pragma unroll
        for (int t = 0; t < 8; ++t) {
            bia[t] = bias[s * DH + t * 16 + r16];
            gam[t] = gamma[(size_t)(s * NL + 0) * DH + t * 16 + r16];
            bet[t] = beta[(size_t)(s * NL + 0) * DH + t * 16 + r16];
        }
        #pragma unroll
        for (int r = 0; r < 4; ++r) {
            float y[8];
            float sm = 0.f, q = 0.f;
            #pragma unroll
            for (int t = 0; t < 8; ++t) {
                y[t] = fmaxf(acc[t][r] + bia[t], 0.f);
                sm += y[t];
                q += y[t] * y[t];
            }
            #pragma unroll
            for (int off = 8; off; off >>= 1) {
                sm += __shfl_xor(sm, off);
                q += __shfl_xor(q, off);
            }
            float mu = sm * (1.f / 128.f);
            float var = q * (1.f / 128.f) - mu * mu;
            float rstd = rsqrtf(var + EPSV);
            int node = g * 16 + g4 * 4 + r;
            if (node < n) {
                float dnode = dis[node];
                #pragma unroll
                for (int t = 0; t < 8; ++t) {
                    float o = ((y[t] - mu) * rstd * gam[t] + bet[t]) * dnode;
                    out[(size_t)node * (NS * DH) + s * DH + t * 16 + r16] = f2bf(o);
                }
            }
        }
    }
}

// ---------------- fused layer-1 GEMM + folded final GEMM (unchanged) ----------------
__global__ __launch_bounds__(256) void k_gemm1q(
        const unsigned short* __restrict__ G, const unsigned short* __restrict__ Whi,
        const unsigned short* __restrict__ Wlo, const unsigned short* __restrict__ Mhi,
        const unsigned short* __restrict__ Mlo, const float* __restrict__ bias,
        const float* __restrict__ gamma, const float* __restrict__ beta,
        const float* __restrict__ dis, unsigned short* __restrict__ q, int n) {
    __shared__ __align__(16) unsigned short sH[4][16][392];
    int wave = threadIdx.x >> 6, lane = threadIdx.x & 63;
    int g = blockIdx.x * 4 + wave;
    if (g * 16 >= n) return;
    int r16 = lane & 15, g4 = lane >> 4;
    int row = g * 16 + r16;
    if (row >= n) row = n - 1;

    for (int s = 0; s < NS; ++s) {
        bf16x8 a[4];
        #pragma unroll
        for (int ks = 0; ks < 4; ++ks)
            a[ks] = *(const bf16x8*)&G[(size_t)row * (NS * DH) + s * DH + ks * 32 + g4 * 8];
        const unsigned short* whi = Whi + (size_t)s * DH * DH;
        const unsigned short* wlo = Wlo + (size_t)s * DH * DH;
        f32x4 acc[8];
        #pragma unroll
        for (int t = 0; t < 8; ++t) acc[t] = (f32x4){0.f, 0.f, 0.f, 0.f};
        #pragma unroll
        for (int ks = 0; ks < 4; ++ks) {
            #pragma unroll
            for (int t = 0; t < 8; ++t) {
                size_t wofs = (size_t)(t * 16 + r16) * DH + ks * 32 + g4 * 8;
                bf16x8 bh = *(const bf16x8*)&whi[wofs];
                bf16x8 bl = *(const bf16x8*)&wlo[wofs];
                acc[t] = __builtin_amdgcn_mfma_f32_16x16x32_bf16(a[ks], bh, acc[t], 0, 0, 0);
                acc[t] = __builtin_amdgcn_mfma_f32_16x16x32_bf16(a[ks], bl, acc[t], 0, 0, 0);
            }
        }
        float bia[8], gam[8], bet[8];
        #pragma unroll
        for (int t = 0; t < 8; ++t) {
            bia[t] = bias[s * DH + t * 16 + r16];
            gam[t] = gamma[(size_t)(s * NL + 1) * DH + t * 16 + r16];
            bet[t] = beta[(size_t)(s * NL + 1) * DH + t * 16 + r16];
        }
        #pragma unroll
        for (int r = 0; r < 4; ++r) {
            float y[8];
            float sm = 0.f, qq = 0.f;
            #pragma unroll
            for (int t = 0; t < 8; ++t) {
                y[t] = fmaxf(acc[t][r] + bia[t], 0.f);
                sm += y[t];
                qq += y[t] * y[t];
            }
            #pragma unroll
            for (int off = 8; off; off >>= 1) {
                sm += __shfl_xor(sm, off);
                qq += __shfl_xor(qq, off);
            }
            float mu = sm * (1.f / 128.f);
            float var = qq * (1.f / 128.f) - mu * mu;
            float rstd = rsqrtf(var + EPSV);
            #pragma unroll
            for (int t = 0; t < 8; ++t) {
                float o = (y[t] - mu) * rstd * gam[t] + bet[t];
                sH[wave][g4 * 4 + r][s * DH + t * 16 + r16] = f2bf(o);
            }
        }
    }
    __syncthreads();
    f32x4 qa[4];
    #pragma unroll
    for (int t = 0; t < 4; ++t) qa[t] = (f32x4){0.f, 0.f, 0.f, 0.f};
    #pragma unroll
    for (int ks = 0; ks < 12; ++ks) {
        bf16x8 av = *(const bf16x8*)&sH[wave][r16][ks * 32 + g4 * 8];
        #pragma unroll
        for (int t = 0; t < 4; ++t) {
            size_t wofs = (size_t)(t * 16 + r16) * (NS * DH) + ks * 32 + g4 * 8;
            bf16x8 bh = *(const bf16x8*)&Mhi[wofs];
            bf16x8 bl = *(const bf16x8*)&Mlo[wofs];
            qa[t] = __builtin_amdgcn_mfma_f32_16x16x32_bf16(av, bh, qa[t], 0, 0, 0);
            qa[t] = __builtin_amdgcn_mfma_f32_16x16x32_bf16(av, bl, qa[t], 0, 0, 0);
        }
    }
    #pragma unroll
    for (int r = 0; r < 4; ++r) {
        int node = g * 16 + g4 * 4 + r;
        if (node < n) {
            float dnode = dis[node];
            #pragma unroll
            for (int t = 0; t < 4; ++t)
                q[(size_t)node * DOUTC + t * 16 + r16] = f2bf(qa[t][r] * dnode);
        }
    }
}

extern "C" void kernel_launch(void* const* d_in, const int* in_sizes, int n_in,
                              void* d_out, int out_size, void* d_ws, size_t ws_size,
                              hipStream_t stream) {
    const float* x    = (const float*)d_in[0];
    const int*   ei   = (const int*)d_in[1];
    const float* W0   = (const float*)d_in[2];
    const float* b0   = (const float*)d_in[3];
    const float* W1   = (const float*)d_in[4];
    const float* b1   = (const float*)d_in[5];
    const float* W2   = (const float*)d_in[6];
    const float* b2   = (const float*)d_in[7];
    const float* gamma= (const float*)d_in[8];
    const float* beta = (const float*)d_in[9];
    const float* Wf   = (const float*)d_in[10];
    const float* bf   = (const float*)d_in[11];
    float* out = (float*)d_out;

    const int n = in_sizes[0] / DIN;
    const int e = in_sizes[1] / 2;
    const int* src = ei;
    const int* dst = ei + e;

    char* ws = (char*)d_ws;
    auto alloc = [&](size_t bytes) {
        char* p = ws;
        ws += (bytes + 255) & ~(size_t)255;
        return p;
    };
    int*   counts   = (int*)alloc((size_t)n * 4);
    int*   cursor   = (int*)alloc((size_t)n * 4);
    int*   rowstart = (int*)alloc((size_t)n * 4);
    int*   bsums    = (int*)alloc(4096);
    float* dis      = (float*)alloc((size_t)n * 4);
    int*   col      = (int*)alloc((size_t)e * 4);
    unsigned short* Wt0hi = (unsigned short*)alloc((size_t)NS * DH * DH * 2);
    unsigned short* Wt0lo = (unsigned short*)alloc((size_t)NS * DH * DH * 2);
    unsigned short* Wt1hi = (unsigned short*)alloc((size_t)NS * DH * DH * 2);
    unsigned short* Wt1lo = (unsigned short*)alloc((size_t)NS * DH * DH * 2);
    unsigned short* Mhi   = (unsigned short*)alloc((size_t)DOUTC * NS * DH * 2);
    unsigned short* Mlo   = (unsigned short*)alloc((size_t)DOUTC * NS * DH * 2);
    float* bcomb    = (float*)alloc(DOUTC * 4);
    unsigned int* xq  = (unsigned int*)alloc((size_t)n * 32 * 4);   // int8 x rows
    float* xs         = (float*)alloc((size_t)n * 4);
    unsigned short* z0    = (unsigned short*)alloc((size_t)n * DH * 2);
    unsigned short* h1cat = (unsigned short*)alloc((size_t)n * NS * DH * 2);
    unsigned int* h1q = (unsigned int*)alloc((size_t)n * 96 * 4);   // int8 h1 rows
    float* hs         = (float*)alloc((size_t)n * 4);
    unsigned short* g1cat = (unsigned short*)alloc((size_t)n * NS * DH * 2);
    unsigned short* q     = (unsigned short*)alloc((size_t)n * DOUTC * 2);
    unsigned int* qq  = (unsigned int*)alloc((size_t)n * 16 * 4);   // int8 q rows
    float* qs2        = (float*)alloc((size_t)n * 4);

    hipMemsetAsync(counts, 0, (size_t)n * 4, stream);

    k_count_r<<<2048, 256, 0, stream>>>(dst, counts, e, n);
    k_dis<<<(n + 255) / 256, 256, 0, stream>>>(counts, dis, n);

    int nb = (n + 511) / 512;
    k_scanA<<<nb, 512, 0, stream>>>(counts, rowstart, bsums, n);
    k_scanB<<<1, 256, 0, stream>>>(bsums, nb);
    k_scanC<<<(n + 255) / 256, 256, 0, stream>>>(rowstart, bsums, n);
    hipMemcpyAsync(cursor, rowstart, (size_t)n * 4, hipMemcpyDeviceToDevice, stream);
    k_fill_r<<<2048, 256, 0, stream>>>(src, dst, cursor, col, e, n);

    k_prep_w<<<(NS * DH * DH + 255) / 256, 256, 0, stream>>>(
        W0, W1, W2, Wf, b2, bf, Wt0hi, Wt0lo, Wt1hi, Wt1lo, Mhi, Mlo, bcomb);
    // x -> int8 rows (scale absorbs dis)
    k_cvtq<<<(n + 3) / 4, 256, 0, stream>>>((const float2*)x, xq, xs, dis, n);

    // z0 = P(x)  via int8 gather
    k_agg128q<<<2048, 256, 0, stream>>>(xq, xs, (unsigned int*)z0,
                                        dis, rowstart, counts, col, n);
    const int GG = (n / 16 + 3) / 4;
    // h1cat = dis * LN(relu(z0 @ W0_s + b0_s)), bf16
    k_gemm0<<<GG, 256, 0, stream>>>(z0, Wt0hi, Wt0lo, b0, gamma, beta, dis, h1cat, n);
    // h1cat -> int8 rows
    k_quant384<<<(n + 7) / 8, 256, 0, stream>>>((const unsigned int*)h1cat, h1q, hs, n);
    // g1cat = P(h1)  via int8 gather (384ch)
    k_agg384q<<<2048, 256, 0, stream>>>(h1q, hs, (unsigned int*)g1cat,
                                        dis, rowstart, counts, col, n);
    // q = dis * concat_s(LN(relu(g1cat_s @ W1_s + b1_s))) @ Mcat
    k_gemm1q<<<GG, 256, 0, stream>>>(g1cat, Wt1hi, Wt1lo, Mhi, Mlo,
                                     b1, gamma, beta, dis, q, n);
    // q -> int8 rows
    k_quant64<<<(n + 15) / 16, 256, 0, stream>>>((const unsigned int*)q, qq, qs2, n);
    // out = P(q) + bcomb  via int8 gather
    k_agg64q<<<2048, 256, 0, stream>>>(qq, qs2, out, bcomb,
                                       dis, rowstart, counts, col, n);
}